// Round 4
// baseline (3914.795 us; speedup 1.0000x reference)
//
#include <hip/hip_runtime.h>
#include <hip/hip_bf16.h>

typedef __hip_bfloat16 bf16;

#define B_    16
#define L_    64
#define N_    1024
#define HANDD 99
#define Jn    21
#define HID   512
#define NLAY  4
#define NHEAD 8
#define DHEAD 64
#define CATD  2273
#define S_    128
#define T_    2048

// workspace float offsets; dtype flag lives in ws[0..15]
#define F_PCT   16
#define F_PCN   (F_PCT + 3145728)
#define F_CATL  (F_PCN + 1048576)
#define F_CATR  (F_CATL + 2327552)
#define F_X     (F_CATR + 2327552)      // x persists; end ~9.9M floats (~40 MB)
// phase-B aliases of the dead pc/cat region:
#define F_QKV   16
#define F_PROBS (F_QKV + 3145728)
#define F_AO    (F_PROBS + 2097152)
#define F_TMP   (F_AO + 1048576)
#define F_H     (F_TMP + 1048576)       // end 7,340,048 < F_X
#define F_FF    16                       // 4,194,304 fl; overlaps only dead qkv/probs

static __device__ __forceinline__ float b2f(bf16 x) { return __bfloat162float(x); }
static __device__ __forceinline__ float ldin(const void* p, size_t i, int isf32) {
    return isf32 ? ((const float*)p)[i] : b2f(((const bf16*)p)[i]);
}

// dtype probe: m_contact ~ U[0,1), 16384 elements. If the buffer is really
// f32, reading it as bf16 exposes mantissa halves with random exponents ->
// values far outside [0,1] with certainty. Catches NaN too.
__global__ __launch_bounds__(256) void detect_kernel(const void* mc, int* flag)
{
    __shared__ int sbad;
    int tid = threadIdx.x;
    if (tid == 0) sbad = 0;
    __syncthreads();
    int bad = 0;
    for (int i = tid; i < 16384; i += 256) {
        float v = b2f(((const bf16*)mc)[i]);
        if (!(v >= -0.02f && v <= 1.02f)) bad = 1;
    }
    if (bad) atomicOr(&sbad, 1);
    __syncthreads();
    if (tid == 0) flag[0] = sbad ? 1 : 0;
}

__global__ __launch_bounds__(256) void pct_kernel(
    const void* __restrict__ x_obj, const void* __restrict__ pc,
    float* __restrict__ pc_t, float* __restrict__ pcn, const int* __restrict__ dtf)
{
    int isf32 = dtf[0];
    int bl = blockIdx.x;
    int b  = bl >> 6;
    size_t xo = (size_t)bl * 10;
    float t0 = ldin(x_obj, xo+0, isf32), t1 = ldin(x_obj, xo+1, isf32), t2 = ldin(x_obj, xo+2, isf32);
    float a1x = ldin(x_obj, xo+3, isf32), a1y = ldin(x_obj, xo+4, isf32), a1z = ldin(x_obj, xo+5, isf32);
    float a2x = ldin(x_obj, xo+6, isf32), a2y = ldin(x_obj, xo+7, isf32), a2z = ldin(x_obj, xo+8, isf32);
    float n1 = sqrtf(a1x*a1x + a1y*a1y + a1z*a1z);
    float b1x = a1x / n1, b1y = a1y / n1, b1z = a1z / n1;
    float d = b1x*a2x + b1y*a2y + b1z*a2z;
    float c2x = a2x - d*b1x, c2y = a2y - d*b1y, c2z = a2z - d*b1z;
    float n2 = sqrtf(c2x*c2x + c2y*c2y + c2z*c2z);
    float b2x = c2x / n2, b2y = c2y / n2, b2z = c2z / n2;
    float b3x = b1y*b2z - b1z*b2y;
    float b3y = b1z*b2x - b1x*b2z;
    float b3z = b1x*b2y - b1y*b2x;
    size_t pcb = (size_t)b * N_ * 3;
    float* outp = pc_t + (size_t)bl * N_ * 3;
    float* outn = pcn  + (size_t)bl * N_;
    for (int n = threadIdx.x; n < N_; n += 256) {
        float p0 = ldin(pc, pcb + n*3+0, isf32);
        float p1 = ldin(pc, pcb + n*3+1, isf32);
        float p2 = ldin(pc, pcb + n*3+2, isf32);
        float q0 = b1x*p0 + b2x*p1 + b3x*p2 + t0;
        float q1 = b1y*p0 + b2y*p1 + b3y*p2 + t1;
        float q2 = b1z*p0 + b2z*p1 + b3z*p2 + t2;
        outp[n*3+0] = q0; outp[n*3+1] = q1; outp[n*3+2] = q2;
        outn[n] = sqrtf(q0*q0 + q1*q1 + q2*q2);
    }
}

// NN contact attention map + concatenated feature row
// layout: [x_hand 99 | j flat 63 | mc 1024 | pcn 1024 | att 63]
__global__ __launch_bounds__(256) void build_cat_kernel(
    const void* __restrict__ x_hand, const void* __restrict__ j_hand,
    const void* __restrict__ mc, const float* __restrict__ pc_t,
    const float* __restrict__ pcn, float* __restrict__ cat, const int* __restrict__ dtf)
{
    int isf32 = dtf[0];
    int bl = blockIdx.x;
    int b  = bl >> 6;
    int tid = threadIdx.x;
    float* row = cat + (size_t)bl * CATD;
    const float* pct = pc_t + (size_t)bl * N_ * 3;

    for (int c = tid; c < HANDD; c += 256)  row[c]        = ldin(x_hand, (size_t)bl*HANDD + c, isf32);
    for (int c = tid; c < 63;    c += 256)  row[99 + c]   = ldin(j_hand, (size_t)bl*63 + c, isf32);
    for (int c = tid; c < N_;    c += 256)  row[162 + c]  = ldin(mc, (size_t)b*N_ + c, isf32);
    for (int c = tid; c < N_;    c += 256)  row[1186 + c] = pcn[(size_t)bl*N_ + c];

    int wave = tid >> 6, lane = tid & 63;
    for (int j = wave; j < Jn; j += 4) {
        float jx = ldin(j_hand, (size_t)bl*63 + j*3 + 0, isf32);
        float jy = ldin(j_hand, (size_t)bl*63 + j*3 + 1, isf32);
        float jz = ldin(j_hand, (size_t)bl*63 + j*3 + 2, isf32);
        float jj = jx*jx + jy*jy + jz*jz;
        float best = 3.4e38f; int bidx = 0x7fffffff;
        for (int n = lane; n < N_; n += 64) {
            float p0 = pct[n*3+0], p1 = pct[n*3+1], p2 = pct[n*3+2];
            float d2 = jj + (p0*p0 + p1*p1 + p2*p2) - 2.f*(jx*p0 + jy*p1 + jz*p2);
            if (d2 < best) { best = d2; bidx = n; }
        }
        // argmin with lowest-index tiebreak (matches np.argmin)
        for (int off = 32; off; off >>= 1) {
            float ob = __shfl_down(best, off, 64);
            int   oi = __shfl_down(bidx, off, 64);
            if (ob < best || (ob == best && oi < bidx)) { best = ob; bidx = oi; }
        }
        bidx = __shfl(bidx, 0, 64);
        if (lane < 3) {
            float jc = (lane == 0) ? jx : ((lane == 1) ? jy : jz);
            float cc = pct[bidx*3 + lane];
            float dd = jc - cc;
            row[2210 + j*3 + lane] = expf(-50.f * dd * dd);
        }
    }
}

#define BM 64
#define BN 64
#define BK 16

// D[M,N] = A[M,K] @ W[K,N] (+bias)(+resid)(relu). W/bias indexed with an
// ELEMENT offset (woff/boff) so per-layer slicing is dtype-agnostic.
// rowmap 1/2: scatter fc rows into interleaved token rows b*128 + 2l + (rowmap-1).
__global__ __launch_bounds__(256) void gemm_f32(
    const float* __restrict__ A, int M, int K,
    const void* __restrict__ W, size_t woff, int Nn,
    const void* __restrict__ bias, size_t boff,
    const float* __restrict__ resid,
    float* __restrict__ D, int relu, int rowmap, const int* __restrict__ dtf)
{
    int isf32 = dtf[0];
    __shared__ __align__(16) float As[BK][BM + 4];
    __shared__ __align__(16) float Bs[BK][BN + 4];
    int tid = threadIdx.x;
    int tx = tid & 15, ty = tid >> 4;
    int row0 = blockIdx.y * BM, col0 = blockIdx.x * BN;
    float acc[4][4] = {};

    for (int k0 = 0; k0 < K; k0 += BK) {
        for (int i = tid; i < BM * BK; i += 256) {
            int r = i >> 4, c = i & 15;
            int gc = k0 + c;
            As[c][r] = (gc < K) ? A[(size_t)(row0 + r) * K + gc] : 0.f;
        }
        for (int i = tid; i < BK * BN; i += 256) {
            int r = i >> 6, c = i & 63;
            int gr = k0 + r, gc = col0 + c;
            Bs[r][c] = (gr < K && gc < Nn) ? ldin(W, woff + (size_t)gr * Nn + gc, isf32) : 0.f;
        }
        __syncthreads();
        #pragma unroll
        for (int kk = 0; kk < BK; kk++) {
            float4 av = *(const float4*)&As[kk][ty * 4];
            float4 bv = *(const float4*)&Bs[kk][tx * 4];
            float a[4] = {av.x, av.y, av.z, av.w};
            float b[4] = {bv.x, bv.y, bv.z, bv.w};
            #pragma unroll
            for (int i = 0; i < 4; i++)
                #pragma unroll
                for (int j = 0; j < 4; j++)
                    acc[i][j] += a[i] * b[j];
        }
        __syncthreads();
    }
    #pragma unroll
    for (int i = 0; i < 4; i++) {
        int r = row0 + ty * 4 + i;
        int orow = r;
        if (rowmap) { int bb = r >> 6, ll = r & 63; orow = bb * S_ + 2 * ll + (rowmap - 1); }
        #pragma unroll
        for (int j = 0; j < 4; j++) {
            int c = col0 + tx * 4 + j;
            if (c >= Nn) continue;
            float v = acc[i][j];
            if (bias)  v += ldin(bias, boff + c, isf32);
            if (resid) v += resid[(size_t)r * Nn + c];
            if (relu)  v = fmaxf(v, 0.f);
            D[(size_t)orow * Nn + c] = v;
        }
    }
}

__global__ __launch_bounds__(256) void pe_add_kernel(float* __restrict__ x)
{
    int idx = blockIdx.x * 256 + threadIdx.x;
    int s = idx >> 9;
    int c = idx & 511;
    int sl = s & (S_ - 1);
    int l = sl >> 1, hand = sl & 1;
    int ci = c & ~1;
    float div = expf((float)ci * (-logf(10000.f) / (float)HID));
    float pf = (c & 1) ? cosf((float)l * div) : sinf((float)l * div);
    float pa = (c & 1) ? cosf((float)hand * div) : sinf((float)hand * div);
    x[idx] += pf + pa;
}

__global__ __launch_bounds__(256) void attn_scores_kernel(
    const float* __restrict__ qkv, float* __restrict__ probs)
{
    int bh = blockIdx.x;
    int b = bh >> 3, h = bh & 7;
    __shared__ float Ks[S_][DHEAD + 1];
    int tid = threadIdx.x;
    for (int i = tid; i < S_ * DHEAD; i += 256) {
        int r = i >> 6, dd = i & 63;
        Ks[r][dd] = qkv[(size_t)(b * S_ + r) * 1536 + 512 + h * DHEAD + dd];
    }
    __syncthreads();
    int wave = tid >> 6, lane = tid & 63;
    int rbase = blockIdx.y * 32;
    for (int r = rbase + wave; r < rbase + 32; r += 4) {
        const float* qrow = &qkv[(size_t)(b * S_ + r) * 1536 + h * DHEAD];
        float s0 = 0.f, s1 = 0.f;
        #pragma unroll 8
        for (int dd = 0; dd < DHEAD; dd++) {
            float qd = qrow[dd];
            s0 += qd * Ks[lane][dd];
            s1 += qd * Ks[lane + 64][dd];
        }
        s0 *= 0.125f; s1 *= 0.125f;
        float m = fmaxf(s0, s1);
        for (int off = 32; off; off >>= 1) m = fmaxf(m, __shfl_down(m, off, 64));
        m = __shfl(m, 0, 64);
        float e0 = expf(s0 - m), e1 = expf(s1 - m);
        float sum = e0 + e1;
        for (int off = 32; off; off >>= 1) sum += __shfl_down(sum, off, 64);
        sum = __shfl(sum, 0, 64);
        float inv = 1.f / sum;
        size_t base = ((size_t)bh * S_ + r) * S_;
        probs[base + lane]      = e0 * inv;
        probs[base + lane + 64] = e1 * inv;
    }
}

__global__ __launch_bounds__(256) void attn_av_kernel(
    const float* __restrict__ qkv, const float* __restrict__ probs,
    float* __restrict__ ao)
{
    int bh = blockIdx.x;
    int b = bh >> 3, h = bh & 7;
    __shared__ float Vs[S_][DHEAD + 1];
    int tid = threadIdx.x;
    for (int i = tid; i < S_ * DHEAD; i += 256) {
        int r = i >> 6, dd = i & 63;
        Vs[r][dd] = qkv[(size_t)(b * S_ + r) * 1536 + 1024 + h * DHEAD + dd];
    }
    __syncthreads();
    int wave = tid >> 6, lane = tid & 63;
    int rbase = blockIdx.y * 32;
    for (int r = rbase + wave; r < rbase + 32; r += 4) {
        const float* prow = &probs[((size_t)bh * S_ + r) * S_];
        float acc = 0.f;
        #pragma unroll 8
        for (int k = 0; k < S_; k++) acc += prow[k] * Vs[k][lane];
        ao[(size_t)(b * S_ + r) * HID + h * DHEAD + lane] = acc;
    }
}

__global__ __launch_bounds__(256) void ln_kernel(
    const float* __restrict__ src, const void* __restrict__ g,
    const void* __restrict__ bb, size_t goff,
    float* __restrict__ dst, const int* __restrict__ dtf)
{
    int isf32 = dtf[0];
    int t = blockIdx.x;
    const float* x = src + (size_t)t * HID;
    float* y = dst + (size_t)t * HID;
    int tid = threadIdx.x, lane = tid & 63, wave = tid >> 6;
    float v0 = x[tid], v1 = x[tid + 256];
    float s = v0 + v1;
    for (int off = 32; off; off >>= 1) s += __shfl_down(s, off, 64);
    __shared__ float wsum[4];
    if (lane == 0) wsum[wave] = s;
    __syncthreads();
    float mu = (wsum[0] + wsum[1] + wsum[2] + wsum[3]) * (1.f / 512.f);
    float d0 = v0 - mu, d1 = v1 - mu;
    float q = d0 * d0 + d1 * d1;
    for (int off = 32; off; off >>= 1) q += __shfl_down(q, off, 64);
    __syncthreads();
    if (lane == 0) wsum[wave] = q;
    __syncthreads();
    float var = (wsum[0] + wsum[1] + wsum[2] + wsum[3]) * (1.f / 512.f);
    float rstd = 1.f / sqrtf(var + 1e-5f);
    y[tid]       = d0 * rstd * ldin(g, goff + tid, isf32)       + ldin(bb, goff + tid, isf32);
    y[tid + 256] = d1 * rstd * ldin(g, goff + tid + 256, isf32) + ldin(bb, goff + tid + 256, isf32);
}

__global__ __launch_bounds__(128) void out_gemm_kernel(
    const float* __restrict__ x,
    const void* __restrict__ Wl, const void* __restrict__ bl,
    const void* __restrict__ Wr, const void* __restrict__ br,
    void* __restrict__ out, const int* __restrict__ dtf)
{
    int isf32 = dtf[0];
    int blk = blockIdx.x;
    int hand = blk >> 10;
    int bl_ = blk & 1023;
    int b = bl_ >> 6, l = bl_ & 63;
    const void* W = hand ? Wr : Wl;
    const void* bias = hand ? br : bl;
    int tok = b * S_ + 2 * l + hand;
    const float* xr = x + (size_t)tok * HID;
    int c = threadIdx.x;
    if (c < HANDD) {
        float acc = ldin(bias, c, isf32);
        #pragma unroll 8
        for (int k = 0; k < HID; k++) acc += xr[k] * ldin(W, (size_t)k * HANDD + c, isf32);
        size_t oi = (size_t)hand * (B_ * L_ * HANDD) + (size_t)bl_ * HANDD + c;
        if (isf32) ((float*)out)[oi] = acc;
        else       ((bf16*)out)[oi]  = __float2bfloat16(acc);
    }
}

extern "C" void kernel_launch(void* const* d_in, const int* in_sizes, int n_in,
                              void* d_out, int out_size, void* d_ws, size_t ws_size,
                              hipStream_t stream)
{
    const void* x_lhand = d_in[0];
    const void* x_rhand = d_in[1];
    const void* j_lhand = d_in[2];
    const void* j_rhand = d_in[3];
    const void* m_contact = d_in[4];
    const void* x_obj = d_in[5];
    const void* point_cloud = d_in[6];
    const void* fc_lw = d_in[7];
    const void* fc_lb = d_in[8];
    const void* fc_rw = d_in[9];
    const void* fc_rb = d_in[10];
    const void* out_lw = d_in[11];
    const void* out_lb = d_in[12];
    const void* out_rw = d_in[13];
    const void* out_rb = d_in[14];
    const void* Wqkv = d_in[15];
    const void* bqkv = d_in[16];
    const void* Wo   = d_in[17];
    const void* bo   = d_in[18];
    const void* W1   = d_in[19];
    const void* b1f  = d_in[20];
    const void* W2   = d_in[21];
    const void* b2fp = d_in[22];
    const void* ln1g = d_in[23];
    const void* ln1b = d_in[24];
    const void* ln2g = d_in[25];
    const void* ln2b = d_in[26];

    float* ws = (float*)d_ws;
    int* dtf = (int*)d_ws;
    float* pc_t  = ws + F_PCT;
    float* pcn   = ws + F_PCN;
    float* cat_l = ws + F_CATL;
    float* cat_r = ws + F_CATR;
    float* x     = ws + F_X;
    float* qkv   = ws + F_QKV;
    float* probs = ws + F_PROBS;
    float* ao    = ws + F_AO;
    float* tmp   = ws + F_TMP;
    float* h     = ws + F_H;
    float* ff    = ws + F_FF;

    detect_kernel<<<1, 256, 0, stream>>>(m_contact, dtf);

    pct_kernel<<<B_ * L_, 256, 0, stream>>>(x_obj, point_cloud, pc_t, pcn, dtf);
    build_cat_kernel<<<B_ * L_, 256, 0, stream>>>(x_lhand, j_lhand, m_contact, pc_t, pcn, cat_l, dtf);
    build_cat_kernel<<<B_ * L_, 256, 0, stream>>>(x_rhand, j_rhand, m_contact, pc_t, pcn, cat_r, dtf);

    {
        dim3 g(HID / BN, (B_ * L_) / BM);
        gemm_f32<<<g, 256, 0, stream>>>(cat_l, B_ * L_, CATD, fc_lw, 0, HID, fc_lb, 0, nullptr, x, 0, 1, dtf);
        gemm_f32<<<g, 256, 0, stream>>>(cat_r, B_ * L_, CATD, fc_rw, 0, HID, fc_rb, 0, nullptr, x, 0, 2, dtf);
    }

    pe_add_kernel<<<(T_ * HID) / 256, 256, 0, stream>>>(x);

    for (int i = 0; i < NLAY; i++) {
        size_t oWq = (size_t)i * HID * 1536, obq = (size_t)i * 1536;
        size_t oWo = (size_t)i * HID * HID,  obo = (size_t)i * HID;
        size_t oW1 = (size_t)i * HID * 2048, ob1 = (size_t)i * 2048;
        size_t oW2 = (size_t)i * 2048 * HID, ob2 = (size_t)i * HID;
        size_t oln = (size_t)i * HID;

        dim3 gq(1536 / BN, T_ / BM);
        gemm_f32<<<gq, 256, 0, stream>>>(x, T_, HID, Wqkv, oWq, 1536, bqkv, obq, nullptr, qkv, 0, 0, dtf);

        attn_scores_kernel<<<dim3(B_ * NHEAD, 4), 256, 0, stream>>>(qkv, probs);
        attn_av_kernel<<<dim3(B_ * NHEAD, 4), 256, 0, stream>>>(qkv, probs, ao);

        dim3 go(HID / BN, T_ / BM);
        gemm_f32<<<go, 256, 0, stream>>>(ao, T_, HID, Wo, oWo, HID, bo, obo, x, tmp, 0, 0, dtf);
        ln_kernel<<<T_, 256, 0, stream>>>(tmp, ln1g, ln1b, oln, h, dtf);

        dim3 g1(2048 / BN, T_ / BM);
        gemm_f32<<<g1, 256, 0, stream>>>(h, T_, HID, W1, oW1, 2048, b1f, ob1, nullptr, ff, 1, 0, dtf);
        dim3 g2(HID / BN, T_ / BM);
        gemm_f32<<<g2, 256, 0, stream>>>(ff, T_, 2048, W2, oW2, HID, b2fp, ob2, h, tmp, 0, 0, dtf);
        ln_kernel<<<T_, 256, 0, stream>>>(tmp, ln2g, ln2b, oln, x, dtf);
    }

    out_gemm_kernel<<<2 * B_ * L_, 128, 0, stream>>>(
        x, out_lw, out_lb, out_rw, out_rb, d_out, dtf);
}

// Round 5
// 1541.550 us; speedup vs baseline: 2.5395x; 2.5395x over previous
//
#include <hip/hip_runtime.h>
#include <hip/hip_bf16.h>

typedef __hip_bfloat16 bf16;
typedef __attribute__((ext_vector_type(8))) short short8;
typedef __attribute__((ext_vector_type(4))) float floatx4;

#define B_    16
#define L_    64
#define N_    1024
#define HANDD 99
#define Jn    21
#define HID   512
#define NLAY  4
#define NHEAD 8
#define DHEAD 64
#define CATD  2273
#define CATP  2304
#define S_    128
#define T_    2048

// f32 workspace offsets (floats)
#define F_X     16
#define F_U     1048592
#define F_PCT   (F_U)
#define F_PCN   (F_U + 3145728)
#define F_CATL  (F_U + 4194304)
#define F_CATR  (F_U + 6553600)
#define F_QKV   (F_U)
#define F_PROBS (F_U + 3145728)
#define F_AO    (F_U + 5242880)
#define F_TMP   (F_U + 6291456)
#define F_H     (F_U + 7340032)
#define F_FF    (F_U)
// bf16 weight arena (ushort offsets from wb)
#define WB_F    10000000
#define W_FCL   0
#define W_FCR   1179648
#define W_QKV   2359296
#define W_WO    5505024
#define W_W1    6553600
#define W_W2    10747904

static __device__ __forceinline__ float b2f(bf16 x) { return __bfloat162float(x); }
static __device__ __forceinline__ float ldin(const void* p, size_t i, int isf32) {
    return isf32 ? ((const float*)p)[i] : b2f(((const bf16*)p)[i]);
}
static __device__ __forceinline__ unsigned short f2bf(float f) {
    unsigned int u = __float_as_uint(f);
    unsigned int r = (u + 0x7fffu + ((u >> 16) & 1u)) >> 16;
    return (unsigned short)r;
}

__global__ __launch_bounds__(256) void detect_kernel(const void* mc, int* flag)
{
    __shared__ int sbad;
    int tid = threadIdx.x;
    if (tid == 0) sbad = 0;
    __syncthreads();
    int bad = 0;
    for (int i = tid; i < 16384; i += 256) {
        float v = b2f(((const bf16*)mc)[i]);
        if (!(v >= -0.02f && v <= 1.02f)) bad = 1;
    }
    if (bad) atomicOr(&sbad, 1);
    __syncthreads();
    if (tid == 0) flag[0] = sbad ? 1 : 0;
}

// weight transpose+convert: src [K][N] (f32 or bf16) -> dst [N][Kpad] bf16, zero pad
__global__ __launch_bounds__(256) void wtrans_kernel(
    const void* __restrict__ src, size_t src_layer, int K, int Nn, int Kpad,
    unsigned short* __restrict__ dst, size_t dst_layer, const int* __restrict__ dtf)
{
    int isf32 = dtf[0];
    __shared__ float tile[64][65];
    int lay = blockIdx.z;
    size_t soff = (size_t)lay * src_layer;
    size_t doff = (size_t)lay * dst_layer;
    int n0 = blockIdx.x * 64, k0 = blockIdx.y * 64;
    int a = threadIdx.x & 63, bq = threadIdx.x >> 6;
    for (int r = bq; r < 64; r += 4) {
        int k = k0 + r;
        float v = (k < K) ? ldin(src, soff + (size_t)k * Nn + (n0 + a), isf32) : 0.f;
        tile[r][a] = v;
    }
    __syncthreads();
    for (int r = bq; r < 64; r += 4) {
        dst[doff + (size_t)(n0 + r) * Kpad + k0 + a] = f2bf(tile[a][r]);
    }
}

__global__ __launch_bounds__(256) void pct_kernel(
    const void* __restrict__ x_obj, const void* __restrict__ pc,
    float* __restrict__ pc_t, float* __restrict__ pcn, const int* __restrict__ dtf)
{
    int isf32 = dtf[0];
    int bl = blockIdx.x;
    int b  = bl >> 6;
    size_t xo = (size_t)bl * 10;
    float t0 = ldin(x_obj, xo+0, isf32), t1 = ldin(x_obj, xo+1, isf32), t2 = ldin(x_obj, xo+2, isf32);
    float a1x = ldin(x_obj, xo+3, isf32), a1y = ldin(x_obj, xo+4, isf32), a1z = ldin(x_obj, xo+5, isf32);
    float a2x = ldin(x_obj, xo+6, isf32), a2y = ldin(x_obj, xo+7, isf32), a2z = ldin(x_obj, xo+8, isf32);
    float n1 = sqrtf(a1x*a1x + a1y*a1y + a1z*a1z);
    float b1x = a1x / n1, b1y = a1y / n1, b1z = a1z / n1;
    float d = b1x*a2x + b1y*a2y + b1z*a2z;
    float c2x = a2x - d*b1x, c2y = a2y - d*b1y, c2z = a2z - d*b1z;
    float n2 = sqrtf(c2x*c2x + c2y*c2y + c2z*c2z);
    float b2x = c2x / n2, b2y = c2y / n2, b2z = c2z / n2;
    float b3x = b1y*b2z - b1z*b2y;
    float b3y = b1z*b2x - b1x*b2z;
    float b3z = b1x*b2y - b1y*b2x;
    size_t pcb = (size_t)b * N_ * 3;
    float* outp = pc_t + (size_t)bl * N_ * 3;
    float* outn = pcn  + (size_t)bl * N_;
    for (int n = threadIdx.x; n < N_; n += 256) {
        float p0 = ldin(pc, pcb + n*3+0, isf32);
        float p1 = ldin(pc, pcb + n*3+1, isf32);
        float p2 = ldin(pc, pcb + n*3+2, isf32);
        float q0 = b1x*p0 + b2x*p1 + b3x*p2 + t0;
        float q1 = b1y*p0 + b2y*p1 + b3y*p2 + t1;
        float q2 = b1z*p0 + b2z*p1 + b3z*p2 + t2;
        outp[n*3+0] = q0; outp[n*3+1] = q1; outp[n*3+2] = q2;
        outn[n] = sqrtf(q0*q0 + q1*q1 + q2*q2);
    }
}

// feature row: [x_hand 99 | j 63 | mc 1024 | pcn 1024 | att 63 | pad->2304]
__global__ __launch_bounds__(256) void build_cat_kernel(
    const void* __restrict__ x_hand, const void* __restrict__ j_hand,
    const void* __restrict__ mc, const float* __restrict__ pc_t,
    const float* __restrict__ pcn, float* __restrict__ cat, const int* __restrict__ dtf)
{
    int isf32 = dtf[0];
    int bl = blockIdx.x;
    int b  = bl >> 6;
    int tid = threadIdx.x;
    float* row = cat + (size_t)bl * CATP;
    const float* pct = pc_t + (size_t)bl * N_ * 3;

    for (int c = tid; c < HANDD; c += 256)  row[c]        = ldin(x_hand, (size_t)bl*HANDD + c, isf32);
    for (int c = tid; c < 63;    c += 256)  row[99 + c]   = ldin(j_hand, (size_t)bl*63 + c, isf32);
    for (int c = tid; c < N_;    c += 256)  row[162 + c]  = ldin(mc, (size_t)b*N_ + c, isf32);
    for (int c = tid; c < N_;    c += 256)  row[1186 + c] = pcn[(size_t)bl*N_ + c];
    for (int c = CATD + tid; c < CATP; c += 256) row[c] = 0.f;

    int wave = tid >> 6, lane = tid & 63;
    for (int j = wave; j < Jn; j += 4) {
        float jx = ldin(j_hand, (size_t)bl*63 + j*3 + 0, isf32);
        float jy = ldin(j_hand, (size_t)bl*63 + j*3 + 1, isf32);
        float jz = ldin(j_hand, (size_t)bl*63 + j*3 + 2, isf32);
        float jj = jx*jx + jy*jy + jz*jz;
        float best = 3.4e38f; int bidx = 0x7fffffff;
        for (int n = lane; n < N_; n += 64) {
            float p0 = pct[n*3+0], p1 = pct[n*3+1], p2 = pct[n*3+2];
            float d2 = jj + (p0*p0 + p1*p1 + p2*p2) - 2.f*(jx*p0 + jy*p1 + jz*p2);
            if (d2 < best) { best = d2; bidx = n; }
        }
        for (int off = 32; off; off >>= 1) {
            float ob = __shfl_down(best, off, 64);
            int   oi = __shfl_down(bidx, off, 64);
            if (ob < best || (ob == best && oi < bidx)) { best = ob; bidx = oi; }
        }
        bidx = __shfl(bidx, 0, 64);
        if (lane < 3) {
            float jc = (lane == 0) ? jx : ((lane == 1) ? jy : jz);
            float cc = pct[bidx*3 + lane];
            float dd = jc - cc;
            row[2210 + j*3 + lane] = expf(-50.f * dd * dd);
        }
    }
}

// MFMA GEMM: D[M,Nn] = A[M,K](f32, lda=K) @ Wt[Nn][K](bf16, pre-transposed)
// 128x128 tile, BK=32, 4 waves, 4x4 mfma(16x16x32) per wave.
#define ASTR 40

__global__ __launch_bounds__(256) void gemm_mfma(
    const float* __restrict__ A, int K,
    const unsigned short* __restrict__ Wt, size_t wtoff, int Nn,
    const void* __restrict__ bias, size_t boff,
    const float* __restrict__ resid,
    float* __restrict__ D, int relu, int rowmap, const int* __restrict__ dtf)
{
    __shared__ short As[128 * ASTR];
    __shared__ short Bs[128 * ASTR];
    int tid = threadIdx.x;
    int wave = tid >> 6, lane = tid & 63;
    int wr = wave >> 1, wc = wave & 1;
    int quad = lane >> 4, l16 = lane & 15;
    int row0 = blockIdx.y * 128, col0 = blockIdx.x * 128;

    floatx4 acc[4][4];
    #pragma unroll
    for (int i = 0; i < 4; i++)
        #pragma unroll
        for (int j = 0; j < 4; j++)
            acc[i][j] = (floatx4){0.f, 0.f, 0.f, 0.f};

    int sm = tid >> 1;            // 0..127
    int sk = (tid & 1) * 16;      // 0 or 16
    const unsigned short* wbase = Wt + wtoff;

    for (int k0 = 0; k0 < K; k0 += 32) {
        // stage A: 16 f32 -> 16 bf16
        const float* ap = A + (size_t)(row0 + sm) * K + k0 + sk;
        float4 f0 = *(const float4*)(ap);
        float4 f1 = *(const float4*)(ap + 4);
        float4 f2 = *(const float4*)(ap + 8);
        float4 f3 = *(const float4*)(ap + 12);
        short8 v0, v1;
        v0[0] = (short)f2bf(f0.x); v0[1] = (short)f2bf(f0.y);
        v0[2] = (short)f2bf(f0.z); v0[3] = (short)f2bf(f0.w);
        v0[4] = (short)f2bf(f1.x); v0[5] = (short)f2bf(f1.y);
        v0[6] = (short)f2bf(f1.z); v0[7] = (short)f2bf(f1.w);
        v1[0] = (short)f2bf(f2.x); v1[1] = (short)f2bf(f2.y);
        v1[2] = (short)f2bf(f2.z); v1[3] = (short)f2bf(f2.w);
        v1[4] = (short)f2bf(f3.x); v1[5] = (short)f2bf(f3.y);
        v1[6] = (short)f2bf(f3.z); v1[7] = (short)f2bf(f3.w);
        *(short8*)&As[sm * ASTR + sk]     = v0;
        *(short8*)&As[sm * ASTR + sk + 8] = v1;
        // stage B: 16 bf16 (contiguous)
        const unsigned short* bp = wbase + (size_t)(col0 + sm) * K + k0 + sk;
        uint4 b0 = *(const uint4*)(bp);
        uint4 b1 = *(const uint4*)(bp + 8);
        *(uint4*)&Bs[sm * ASTR + sk]     = b0;
        *(uint4*)&Bs[sm * ASTR + sk + 8] = b1;
        __syncthreads();

        short8 af[4], bfr[4];
        #pragma unroll
        for (int mi = 0; mi < 4; mi++)
            af[mi] = *(const short8*)&As[(wr*64 + mi*16 + l16) * ASTR + quad*8];
        #pragma unroll
        for (int ni = 0; ni < 4; ni++)
            bfr[ni] = *(const short8*)&Bs[(wc*64 + ni*16 + l16) * ASTR + quad*8];
        #pragma unroll
        for (int mi = 0; mi < 4; mi++)
            #pragma unroll
            for (int ni = 0; ni < 4; ni++)
                acc[mi][ni] = __builtin_amdgcn_mfma_f32_16x16x32_bf16(
                    af[mi], bfr[ni], acc[mi][ni], 0, 0, 0);
        __syncthreads();
    }

    int isf32 = dtf[0];
    #pragma unroll
    for (int ni = 0; ni < 4; ni++) {
        int c = col0 + wc*64 + ni*16 + l16;
        float bv = bias ? ldin(bias, boff + c, isf32) : 0.f;
        #pragma unroll
        for (int mi = 0; mi < 4; mi++) {
            #pragma unroll
            for (int reg = 0; reg < 4; reg++) {
                int r = row0 + wr*64 + mi*16 + quad*4 + reg;
                float v = acc[mi][ni][reg] + bv;
                if (resid) v += resid[(size_t)r * Nn + c];
                if (relu)  v = fmaxf(v, 0.f);
                int orow = r;
                if (rowmap) { int bb = r >> 6, ll = r & 63; orow = bb * S_ + 2 * ll + (rowmap - 1); }
                D[(size_t)orow * Nn + c] = v;
            }
        }
    }
}

__global__ __launch_bounds__(256) void pe_add_kernel(float* __restrict__ x)
{
    int idx = blockIdx.x * 256 + threadIdx.x;
    int s = idx >> 9;
    int c = idx & 511;
    int sl = s & (S_ - 1);
    int l = sl >> 1, hand = sl & 1;
    int ci = c & ~1;
    float div = expf((float)ci * (-logf(10000.f) / (float)HID));
    float pf = (c & 1) ? cosf((float)l * div) : sinf((float)l * div);
    float pa = (c & 1) ? cosf((float)hand * div) : sinf((float)hand * div);
    x[idx] += pf + pa;
}

__global__ __launch_bounds__(256) void attn_scores_kernel(
    const float* __restrict__ qkv, float* __restrict__ probs)
{
    int bh = blockIdx.x;
    int b = bh >> 3, h = bh & 7;
    __shared__ float Ks[S_][DHEAD + 1];
    int tid = threadIdx.x;
    for (int i = tid; i < S_ * DHEAD; i += 256) {
        int r = i >> 6, dd = i & 63;
        Ks[r][dd] = qkv[(size_t)(b * S_ + r) * 1536 + 512 + h * DHEAD + dd];
    }
    __syncthreads();
    int wave = tid >> 6, lane = tid & 63;
    int rbase = blockIdx.y * 32;
    for (int r = rbase + wave; r < rbase + 32; r += 4) {
        const float* qrow = &qkv[(size_t)(b * S_ + r) * 1536 + h * DHEAD];
        float s0 = 0.f, s1 = 0.f;
        #pragma unroll 8
        for (int dd = 0; dd < DHEAD; dd++) {
            float qd = qrow[dd];
            s0 += qd * Ks[lane][dd];
            s1 += qd * Ks[lane + 64][dd];
        }
        s0 *= 0.125f; s1 *= 0.125f;
        float m = fmaxf(s0, s1);
        for (int off = 32; off; off >>= 1) m = fmaxf(m, __shfl_down(m, off, 64));
        m = __shfl(m, 0, 64);
        float e0 = expf(s0 - m), e1 = expf(s1 - m);
        float sum = e0 + e1;
        for (int off = 32; off; off >>= 1) sum += __shfl_down(sum, off, 64);
        sum = __shfl(sum, 0, 64);
        float inv = 1.f / sum;
        size_t base = ((size_t)bh * S_ + r) * S_;
        probs[base + lane]      = e0 * inv;
        probs[base + lane + 64] = e1 * inv;
    }
}

__global__ __launch_bounds__(256) void attn_av_kernel(
    const float* __restrict__ qkv, const float* __restrict__ probs,
    float* __restrict__ ao)
{
    int bh = blockIdx.x;
    int b = bh >> 3, h = bh & 7;
    __shared__ float Vs[S_][DHEAD + 1];
    int tid = threadIdx.x;
    for (int i = tid; i < S_ * DHEAD; i += 256) {
        int r = i >> 6, dd = i & 63;
        Vs[r][dd] = qkv[(size_t)(b * S_ + r) * 1536 + 1024 + h * DHEAD + dd];
    }
    __syncthreads();
    int wave = tid >> 6, lane = tid & 63;
    int rbase = blockIdx.y * 32;
    for (int r = rbase + wave; r < rbase + 32; r += 4) {
        const float* prow = &probs[((size_t)bh * S_ + r) * S_];
        float acc = 0.f;
        #pragma unroll 8
        for (int k = 0; k < S_; k++) acc += prow[k] * Vs[k][lane];
        ao[(size_t)(b * S_ + r) * HID + h * DHEAD + lane] = acc;
    }
}

__global__ __launch_bounds__(256) void ln_kernel(
    const float* __restrict__ src, const void* __restrict__ g,
    const void* __restrict__ bb, size_t goff,
    float* __restrict__ dst, const int* __restrict__ dtf)
{
    int isf32 = dtf[0];
    int t = blockIdx.x;
    const float* x = src + (size_t)t * HID;
    float* y = dst + (size_t)t * HID;
    int tid = threadIdx.x, lane = tid & 63, wave = tid >> 6;
    float v0 = x[tid], v1 = x[tid + 256];
    float s = v0 + v1;
    for (int off = 32; off; off >>= 1) s += __shfl_down(s, off, 64);
    __shared__ float wsum[4];
    if (lane == 0) wsum[wave] = s;
    __syncthreads();
    float mu = (wsum[0] + wsum[1] + wsum[2] + wsum[3]) * (1.f / 512.f);
    float d0 = v0 - mu, d1 = v1 - mu;
    float q = d0 * d0 + d1 * d1;
    for (int off = 32; off; off >>= 1) q += __shfl_down(q, off, 64);
    __syncthreads();
    if (lane == 0) wsum[wave] = q;
    __syncthreads();
    float var = (wsum[0] + wsum[1] + wsum[2] + wsum[3]) * (1.f / 512.f);
    float rstd = 1.f / sqrtf(var + 1e-5f);
    y[tid]       = d0 * rstd * ldin(g, goff + tid, isf32)       + ldin(bb, goff + tid, isf32);
    y[tid + 256] = d1 * rstd * ldin(g, goff + tid + 256, isf32) + ldin(bb, goff + tid + 256, isf32);
}

__global__ __launch_bounds__(128) void out_gemm_kernel(
    const float* __restrict__ x,
    const void* __restrict__ Wl, const void* __restrict__ bl,
    const void* __restrict__ Wr, const void* __restrict__ br,
    void* __restrict__ out, const int* __restrict__ dtf)
{
    int isf32 = dtf[0];
    int blk = blockIdx.x;
    int hand = blk >> 10;
    int bl_ = blk & 1023;
    int b = bl_ >> 6, l = bl_ & 63;
    const void* W = hand ? Wr : Wl;
    const void* bias = hand ? br : bl;
    int tok = b * S_ + 2 * l + hand;
    const float* xr = x + (size_t)tok * HID;
    int c = threadIdx.x;
    if (c < HANDD) {
        float acc = ldin(bias, c, isf32);
        #pragma unroll 8
        for (int k = 0; k < HID; k++) acc += xr[k] * ldin(W, (size_t)k * HANDD + c, isf32);
        size_t oi = (size_t)hand * (B_ * L_ * HANDD) + (size_t)bl_ * HANDD + c;
        if (isf32) ((float*)out)[oi] = acc;
        else       ((bf16*)out)[oi]  = __float2bfloat16(acc);
    }
}

extern "C" void kernel_launch(void* const* d_in, const int* in_sizes, int n_in,
                              void* d_out, int out_size, void* d_ws, size_t ws_size,
                              hipStream_t stream)
{
    const void* x_lhand = d_in[0];
    const void* x_rhand = d_in[1];
    const void* j_lhand = d_in[2];
    const void* j_rhand = d_in[3];
    const void* m_contact = d_in[4];
    const void* x_obj = d_in[5];
    const void* point_cloud = d_in[6];
    const void* fc_lw = d_in[7];
    const void* fc_lb = d_in[8];
    const void* fc_rw = d_in[9];
    const void* fc_rb = d_in[10];
    const void* out_lw = d_in[11];
    const void* out_lb = d_in[12];
    const void* out_rw = d_in[13];
    const void* out_rb = d_in[14];
    const void* Wqkv = d_in[15];
    const void* bqkv = d_in[16];
    const void* Wo   = d_in[17];
    const void* bo   = d_in[18];
    const void* W1   = d_in[19];
    const void* b1f  = d_in[20];
    const void* W2   = d_in[21];
    const void* b2fp = d_in[22];
    const void* ln1g = d_in[23];
    const void* ln1b = d_in[24];
    const void* ln2g = d_in[25];
    const void* ln2b = d_in[26];

    float* ws = (float*)d_ws;
    int* dtf = (int*)d_ws;
    float* x     = ws + F_X;
    float* pc_t  = ws + F_PCT;
    float* pcn   = ws + F_PCN;
    float* cat_l = ws + F_CATL;
    float* cat_r = ws + F_CATR;
    float* qkv   = ws + F_QKV;
    float* probs = ws + F_PROBS;
    float* ao    = ws + F_AO;
    float* tmp   = ws + F_TMP;
    float* h     = ws + F_H;
    float* ff    = ws + F_FF;
    unsigned short* wb = (unsigned short*)(ws + WB_F);

    detect_kernel<<<1, 256, 0, stream>>>(m_contact, dtf);

    // weight transposes (bf16 [N][Kpad])
    wtrans_kernel<<<dim3(8, 36, 1), 256, 0, stream>>>(fc_lw, 0, CATD, HID, CATP, wb + W_FCL, 0, dtf);
    wtrans_kernel<<<dim3(8, 36, 1), 256, 0, stream>>>(fc_rw, 0, CATD, HID, CATP, wb + W_FCR, 0, dtf);
    wtrans_kernel<<<dim3(24, 8, NLAY), 256, 0, stream>>>(Wqkv, (size_t)HID*1536, HID, 1536, HID, wb + W_QKV, (size_t)1536*HID, dtf);
    wtrans_kernel<<<dim3(8, 8, NLAY), 256, 0, stream>>>(Wo, (size_t)HID*HID, HID, HID, HID, wb + W_WO, (size_t)HID*HID, dtf);
    wtrans_kernel<<<dim3(32, 8, NLAY), 256, 0, stream>>>(W1, (size_t)HID*2048, HID, 2048, HID, wb + W_W1, (size_t)2048*HID, dtf);
    wtrans_kernel<<<dim3(8, 32, NLAY), 256, 0, stream>>>(W2, (size_t)2048*HID, 2048, HID, 2048, wb + W_W2, (size_t)HID*2048, dtf);

    pct_kernel<<<B_ * L_, 256, 0, stream>>>(x_obj, point_cloud, pc_t, pcn, dtf);
    build_cat_kernel<<<B_ * L_, 256, 0, stream>>>(x_lhand, j_lhand, m_contact, pc_t, pcn, cat_l, dtf);
    build_cat_kernel<<<B_ * L_, 256, 0, stream>>>(x_rhand, j_rhand, m_contact, pc_t, pcn, cat_r, dtf);

    // fc projections -> interleaved x
    gemm_mfma<<<dim3(4, 8), 256, 0, stream>>>(cat_l, CATP, wb, W_FCL, HID, fc_lb, 0, nullptr, x, 0, 1, dtf);
    gemm_mfma<<<dim3(4, 8), 256, 0, stream>>>(cat_r, CATP, wb, W_FCR, HID, fc_rb, 0, nullptr, x, 0, 2, dtf);

    pe_add_kernel<<<(T_ * HID) / 256, 256, 0, stream>>>(x);

    for (int i = 0; i < NLAY; i++) {
        size_t oWq = (size_t)W_QKV + (size_t)i * 1536 * HID, obq = (size_t)i * 1536;
        size_t oWo = (size_t)W_WO + (size_t)i * HID * HID,   obo = (size_t)i * HID;
        size_t oW1 = (size_t)W_W1 + (size_t)i * 2048 * HID,  ob1 = (size_t)i * 2048;
        size_t oW2 = (size_t)W_W2 + (size_t)i * HID * 2048,  ob2 = (size_t)i * HID;
        size_t oln = (size_t)i * HID;

        gemm_mfma<<<dim3(12, 16), 256, 0, stream>>>(x, HID, wb, oWq, 1536, bqkv, obq, nullptr, qkv, 0, 0, dtf);

        attn_scores_kernel<<<dim3(B_ * NHEAD, 4), 256, 0, stream>>>(qkv, probs);
        attn_av_kernel<<<dim3(B_ * NHEAD, 4), 256, 0, stream>>>(qkv, probs, ao);

        gemm_mfma<<<dim3(4, 16), 256, 0, stream>>>(ao, HID, wb, oWo, HID, bo, obo, x, tmp, 0, 0, dtf);
        ln_kernel<<<T_, 256, 0, stream>>>(tmp, ln1g, ln1b, oln, h, dtf);

        gemm_mfma<<<dim3(16, 16), 256, 0, stream>>>(h, HID, wb, oW1, 2048, b1f, ob1, nullptr, ff, 1, 0, dtf);
        gemm_mfma<<<dim3(4, 16), 256, 0, stream>>>(ff, 2048, wb, oW2, HID, b2fp, ob2, h, tmp, 0, 0, dtf);
        ln_kernel<<<T_, 256, 0, stream>>>(tmp, ln2g, ln2b, oln, x, dtf);
    }

    out_gemm_kernel<<<2 * B_ * L_, 128, 0, stream>>>(
        x, out_lw, out_lb, out_rw, out_rb, d_out, dtf);
}

// Round 6
// 1532.696 us; speedup vs baseline: 2.5542x; 1.0058x over previous
//
#include <hip/hip_runtime.h>
#include <hip/hip_bf16.h>

typedef __hip_bfloat16 bf16;
typedef __attribute__((ext_vector_type(8))) short short8;
typedef __attribute__((ext_vector_type(4))) float floatx4;

#define B_    16
#define L_    64
#define N_    1024
#define HANDD 99
#define Jn    21
#define HID   512
#define NLAY  4
#define NHEAD 8
#define DHEAD 64
#define CATD  2273
#define CATP  2304
#define S_    128
#define T_    2048

// f32 workspace offsets (floats)
#define F_X     16
#define F_U     1048592
#define F_PCT   (F_U)
#define F_PCN   (F_U + 3145728)
#define F_CATL  (F_U + 4194304)
#define F_CATR  (F_U + 6553600)
#define F_QKV   (F_U)
#define F_PROBS (F_U + 3145728)
#define F_AO    (F_U + 5242880)
#define F_TMP   (F_U + 6291456)
#define F_H     (F_U + 7340032)
#define F_FF    (F_U)
// bf16 weight arena (ushort offsets from wb)
#define WB_F    10000000
#define W_FCL   0
#define W_FCR   1179648
#define W_QKV   2359296
#define W_WO    5505024
#define W_W1    6553600
#define W_W2    10747904

static __device__ __forceinline__ float b2f(bf16 x) { return __bfloat162float(x); }
static __device__ __forceinline__ float ldin(const void* p, size_t i, int isf32) {
    return isf32 ? ((const float*)p)[i] : b2f(((const bf16*)p)[i]);
}
static __device__ __forceinline__ unsigned short f2bf(float f) {
    unsigned int u = __float_as_uint(f);
    unsigned int r = (u + 0x7fffu + ((u >> 16) & 1u)) >> 16;
    return (unsigned short)r;
}

__global__ __launch_bounds__(256) void detect_kernel(const void* mc, int* flag)
{
    __shared__ int sbad;
    int tid = threadIdx.x;
    if (tid == 0) sbad = 0;
    __syncthreads();
    int bad = 0;
    for (int i = tid; i < 16384; i += 256) {
        float v = b2f(((const bf16*)mc)[i]);
        if (!(v >= -0.02f && v <= 1.02f)) bad = 1;
    }
    if (bad) atomicOr(&sbad, 1);
    __syncthreads();
    if (tid == 0) flag[0] = sbad ? 1 : 0;
}

// weight transpose+convert: src [K][N] (f32 or bf16) -> dst [N][Kpad] bf16, zero pad
__global__ __launch_bounds__(256) void wtrans_kernel(
    const void* __restrict__ src, size_t src_layer, int K, int Nn, int Kpad,
    unsigned short* __restrict__ dst, size_t dst_layer, const int* __restrict__ dtf)
{
    int isf32 = dtf[0];
    __shared__ float tile[64][65];
    int lay = blockIdx.z;
    size_t soff = (size_t)lay * src_layer;
    size_t doff = (size_t)lay * dst_layer;
    int n0 = blockIdx.x * 64, k0 = blockIdx.y * 64;
    int a = threadIdx.x & 63, bq = threadIdx.x >> 6;
    for (int r = bq; r < 64; r += 4) {
        int k = k0 + r;
        float v = (k < K) ? ldin(src, soff + (size_t)k * Nn + (n0 + a), isf32) : 0.f;
        tile[r][a] = v;
    }
    __syncthreads();
    for (int r = bq; r < 64; r += 4) {
        dst[doff + (size_t)(n0 + r) * Kpad + k0 + a] = f2bf(tile[a][r]);
    }
}

__global__ __launch_bounds__(256) void pct_kernel(
    const void* __restrict__ x_obj, const void* __restrict__ pc,
    float* __restrict__ pc_t, float* __restrict__ pcn, const int* __restrict__ dtf)
{
    int isf32 = dtf[0];
    int bl = blockIdx.x;
    int b  = bl >> 6;
    size_t xo = (size_t)bl * 10;
    float t0 = ldin(x_obj, xo+0, isf32), t1 = ldin(x_obj, xo+1, isf32), t2 = ldin(x_obj, xo+2, isf32);
    float a1x = ldin(x_obj, xo+3, isf32), a1y = ldin(x_obj, xo+4, isf32), a1z = ldin(x_obj, xo+5, isf32);
    float a2x = ldin(x_obj, xo+6, isf32), a2y = ldin(x_obj, xo+7, isf32), a2z = ldin(x_obj, xo+8, isf32);
    float n1 = sqrtf(a1x*a1x + a1y*a1y + a1z*a1z);
    float b1x = a1x / n1, b1y = a1y / n1, b1z = a1z / n1;
    float d = b1x*a2x + b1y*a2y + b1z*a2z;
    float c2x = a2x - d*b1x, c2y = a2y - d*b1y, c2z = a2z - d*b1z;
    float n2 = sqrtf(c2x*c2x + c2y*c2y + c2z*c2z);
    float b2x = c2x / n2, b2y = c2y / n2, b2z = c2z / n2;
    float b3x = b1y*b2z - b1z*b2y;
    float b3y = b1z*b2x - b1x*b2z;
    float b3z = b1x*b2y - b1y*b2x;
    size_t pcb = (size_t)b * N_ * 3;
    float* outp = pc_t + (size_t)bl * N_ * 3;
    float* outn = pcn  + (size_t)bl * N_;
    for (int n = threadIdx.x; n < N_; n += 256) {
        float p0 = ldin(pc, pcb + n*3+0, isf32);
        float p1 = ldin(pc, pcb + n*3+1, isf32);
        float p2 = ldin(pc, pcb + n*3+2, isf32);
        float q0 = b1x*p0 + b2x*p1 + b3x*p2 + t0;
        float q1 = b1y*p0 + b2y*p1 + b3y*p2 + t1;
        float q2 = b1z*p0 + b2z*p1 + b3z*p2 + t2;
        outp[n*3+0] = q0; outp[n*3+1] = q1; outp[n*3+2] = q2;
        outn[n] = sqrtf(q0*q0 + q1*q1 + q2*q2);
    }
}

// feature row: [x_hand 99 | j 63 | mc 1024 | pcn 1024 | att 63 | pad->2304]
// blockIdx.y = hand (0=left, 1=right)
__global__ __launch_bounds__(256) void build_cat_kernel(
    const void* __restrict__ x_l, const void* __restrict__ j_l,
    const void* __restrict__ x_r, const void* __restrict__ j_r,
    const void* __restrict__ mc, const float* __restrict__ pc_t,
    const float* __restrict__ pcn, float* __restrict__ cat_l,
    float* __restrict__ cat_r, const int* __restrict__ dtf)
{
    int isf32 = dtf[0];
    int hand = blockIdx.y;
    const void* x_hand = hand ? x_r : x_l;
    const void* j_hand = hand ? j_r : j_l;
    float* cat = hand ? cat_r : cat_l;
    int bl = blockIdx.x;
    int b  = bl >> 6;
    int tid = threadIdx.x;
    float* row = cat + (size_t)bl * CATP;
    const float* pct = pc_t + (size_t)bl * N_ * 3;

    for (int c = tid; c < HANDD; c += 256)  row[c]        = ldin(x_hand, (size_t)bl*HANDD + c, isf32);
    for (int c = tid; c < 63;    c += 256)  row[99 + c]   = ldin(j_hand, (size_t)bl*63 + c, isf32);
    for (int c = tid; c < N_;    c += 256)  row[162 + c]  = ldin(mc, (size_t)b*N_ + c, isf32);
    for (int c = tid; c < N_;    c += 256)  row[1186 + c] = pcn[(size_t)bl*N_ + c];
    for (int c = CATD + tid; c < CATP; c += 256) row[c] = 0.f;

    int wave = tid >> 6, lane = tid & 63;
    for (int j = wave; j < Jn; j += 4) {
        float jx = ldin(j_hand, (size_t)bl*63 + j*3 + 0, isf32);
        float jy = ldin(j_hand, (size_t)bl*63 + j*3 + 1, isf32);
        float jz = ldin(j_hand, (size_t)bl*63 + j*3 + 2, isf32);
        float jj = jx*jx + jy*jy + jz*jz;
        float best = 3.4e38f; int bidx = 0x7fffffff;
        for (int n = lane; n < N_; n += 64) {
            float p0 = pct[n*3+0], p1 = pct[n*3+1], p2 = pct[n*3+2];
            float d2 = jj + (p0*p0 + p1*p1 + p2*p2) - 2.f*(jx*p0 + jy*p1 + jz*p2);
            if (d2 < best) { best = d2; bidx = n; }
        }
        for (int off = 32; off; off >>= 1) {
            float ob = __shfl_down(best, off, 64);
            int   oi = __shfl_down(bidx, off, 64);
            if (ob < best || (ob == best && oi < bidx)) { best = ob; bidx = oi; }
        }
        bidx = __shfl(bidx, 0, 64);
        if (lane < 3) {
            float jc = (lane == 0) ? jx : ((lane == 1) ? jy : jz);
            float cc = pct[bidx*3 + lane];
            float dd = jc - cc;
            row[2210 + j*3 + lane] = expf(-50.f * dd * dd);
        }
    }
}

// MFMA GEMM with register-prefetch pipeline.
// D[M,Nn] = A[M,K](f32) @ Wt[Nn][K](bf16). 128x128 tile, BK=32.
// rowmap 1/2: scatter rows + fused sinusoidal PE add (fc epilogue).
#define ASTR 40

__global__ __launch_bounds__(256) void gemm_mfma(
    const float* __restrict__ A, int K,
    const unsigned short* __restrict__ Wt, size_t wtoff, int Nn,
    const void* __restrict__ bias, size_t boff,
    const float* __restrict__ resid,
    float* __restrict__ D, int relu, int rowmap, const int* __restrict__ dtf)
{
    __shared__ short As[128 * ASTR];
    __shared__ short Bs[128 * ASTR];
    int tid = threadIdx.x;
    int wave = tid >> 6, lane = tid & 63;
    int wr = wave >> 1, wc = wave & 1;
    int quad = lane >> 4, l16 = lane & 15;
    int row0 = blockIdx.y * 128, col0 = blockIdx.x * 128;

    floatx4 acc[4][4];
    #pragma unroll
    for (int i = 0; i < 4; i++)
        #pragma unroll
        for (int j = 0; j < 4; j++)
            acc[i][j] = (floatx4){0.f, 0.f, 0.f, 0.f};

    int sm = tid >> 1;            // 0..127
    int sk = (tid & 1) * 16;      // 0 or 16
    const unsigned short* wbase = Wt + wtoff;
    const float* aprow = A + (size_t)(row0 + sm) * K + sk;
    const unsigned short* bprow = wbase + (size_t)(col0 + sm) * K + sk;

    // prologue loads (k0 = 0)
    float4 fa0 = *(const float4*)(aprow);
    float4 fa1 = *(const float4*)(aprow + 4);
    float4 fa2 = *(const float4*)(aprow + 8);
    float4 fa3 = *(const float4*)(aprow + 12);
    uint4  wb0 = *(const uint4*)(bprow);
    uint4  wb1 = *(const uint4*)(bprow + 8);

    for (int k0 = 0; k0 < K; k0 += 32) {
        // stage current regs into LDS (f32 -> bf16 pack for A)
        short8 v0, v1;
        v0[0] = (short)f2bf(fa0.x); v0[1] = (short)f2bf(fa0.y);
        v0[2] = (short)f2bf(fa0.z); v0[3] = (short)f2bf(fa0.w);
        v0[4] = (short)f2bf(fa1.x); v0[5] = (short)f2bf(fa1.y);
        v0[6] = (short)f2bf(fa1.z); v0[7] = (short)f2bf(fa1.w);
        v1[0] = (short)f2bf(fa2.x); v1[1] = (short)f2bf(fa2.y);
        v1[2] = (short)f2bf(fa2.z); v1[3] = (short)f2bf(fa2.w);
        v1[4] = (short)f2bf(fa3.x); v1[5] = (short)f2bf(fa3.y);
        v1[6] = (short)f2bf(fa3.z); v1[7] = (short)f2bf(fa3.w);
        *(short8*)&As[sm * ASTR + sk]     = v0;
        *(short8*)&As[sm * ASTR + sk + 8] = v1;
        *(uint4*)&Bs[sm * ASTR + sk]      = wb0;
        *(uint4*)&Bs[sm * ASTR + sk + 8]  = wb1;
        __syncthreads();

        // prefetch next k-tile while computing this one
        if (k0 + 32 < K) {
            const float* ap = aprow + k0 + 32;
            const unsigned short* bp = bprow + k0 + 32;
            fa0 = *(const float4*)(ap);
            fa1 = *(const float4*)(ap + 4);
            fa2 = *(const float4*)(ap + 8);
            fa3 = *(const float4*)(ap + 12);
            wb0 = *(const uint4*)(bp);
            wb1 = *(const uint4*)(bp + 8);
        }

        short8 af[4], bfr[4];
        #pragma unroll
        for (int mi = 0; mi < 4; mi++)
            af[mi] = *(const short8*)&As[(wr*64 + mi*16 + l16) * ASTR + quad*8];
        #pragma unroll
        for (int ni = 0; ni < 4; ni++)
            bfr[ni] = *(const short8*)&Bs[(wc*64 + ni*16 + l16) * ASTR + quad*8];
        #pragma unroll
        for (int mi = 0; mi < 4; mi++)
            #pragma unroll
            for (int ni = 0; ni < 4; ni++)
                acc[mi][ni] = __builtin_amdgcn_mfma_f32_16x16x32_bf16(
                    af[mi], bfr[ni], acc[mi][ni], 0, 0, 0);
        __syncthreads();
    }

    int isf32 = dtf[0];
    #pragma unroll
    for (int ni = 0; ni < 4; ni++) {
        int c = col0 + wc*64 + ni*16 + l16;
        float bv = bias ? ldin(bias, boff + c, isf32) : 0.f;
        // fused PE terms for fc path (rowmap != 0): depend on c and row
        float pe_div = 0.f, pa = 0.f;
        if (rowmap) {
            int ci = c & ~1;
            pe_div = expf((float)ci * (-logf(10000.f) / (float)HID));
            int hand = rowmap - 1;
            pa = (c & 1) ? cosf((float)hand * pe_div) : sinf((float)hand * pe_div);
        }
        #pragma unroll
        for (int mi = 0; mi < 4; mi++) {
            #pragma unroll
            for (int reg = 0; reg < 4; reg++) {
                int r = row0 + wr*64 + mi*16 + quad*4 + reg;
                float v = acc[mi][ni][reg] + bv;
                if (resid) v += resid[(size_t)r * Nn + c];
                if (relu)  v = fmaxf(v, 0.f);
                int orow = r;
                if (rowmap) {
                    int bb = r >> 6, ll = r & 63;
                    orow = bb * S_ + 2 * ll + (rowmap - 1);
                    float pf = (c & 1) ? cosf((float)ll * pe_div) : sinf((float)ll * pe_div);
                    v += pf + pa;
                }
                D[(size_t)orow * Nn + c] = v;
            }
        }
    }
}

__global__ __launch_bounds__(256) void attn_scores_kernel(
    const float* __restrict__ qkv, float* __restrict__ probs)
{
    int bh = blockIdx.x;
    int b = bh >> 3, h = bh & 7;
    __shared__ float Ks[S_][DHEAD + 1];
    int tid = threadIdx.x;
    for (int i = tid; i < S_ * DHEAD; i += 256) {
        int r = i >> 6, dd = i & 63;
        Ks[r][dd] = qkv[(size_t)(b * S_ + r) * 1536 + 512 + h * DHEAD + dd];
    }
    __syncthreads();
    int wave = tid >> 6, lane = tid & 63;
    int rbase = blockIdx.y * 32;
    for (int r = rbase + wave; r < rbase + 32; r += 4) {
        const float* qrow = &qkv[(size_t)(b * S_ + r) * 1536 + h * DHEAD];
        float s0 = 0.f, s1 = 0.f;
        #pragma unroll 8
        for (int dd = 0; dd < DHEAD; dd++) {
            float qd = qrow[dd];
            s0 += qd * Ks[lane][dd];
            s1 += qd * Ks[lane + 64][dd];
        }
        s0 *= 0.125f; s1 *= 0.125f;
        float m = fmaxf(s0, s1);
        for (int off = 32; off; off >>= 1) m = fmaxf(m, __shfl_down(m, off, 64));
        m = __shfl(m, 0, 64);
        float e0 = expf(s0 - m), e1 = expf(s1 - m);
        float sum = e0 + e1;
        for (int off = 32; off; off >>= 1) sum += __shfl_down(sum, off, 64);
        sum = __shfl(sum, 0, 64);
        float inv = 1.f / sum;
        size_t base = ((size_t)bh * S_ + r) * S_;
        probs[base + lane]      = e0 * inv;
        probs[base + lane + 64] = e1 * inv;
    }
}

__global__ __launch_bounds__(256) void attn_av_kernel(
    const float* __restrict__ qkv, const float* __restrict__ probs,
    float* __restrict__ ao)
{
    int bh = blockIdx.x;
    int b = bh >> 3, h = bh & 7;
    __shared__ float Vs[S_][DHEAD + 1];
    int tid = threadIdx.x;
    for (int i = tid; i < S_ * DHEAD; i += 256) {
        int r = i >> 6, dd = i & 63;
        Vs[r][dd] = qkv[(size_t)(b * S_ + r) * 1536 + 1024 + h * DHEAD + dd];
    }
    __syncthreads();
    int wave = tid >> 6, lane = tid & 63;
    int rbase = blockIdx.y * 32;
    for (int r = rbase + wave; r < rbase + 32; r += 4) {
        const float* prow = &probs[((size_t)bh * S_ + r) * S_];
        float acc = 0.f;
        #pragma unroll 8
        for (int k = 0; k < S_; k++) acc += prow[k] * Vs[k][lane];
        ao[(size_t)(b * S_ + r) * HID + h * DHEAD + lane] = acc;
    }
}

__global__ __launch_bounds__(256) void ln_kernel(
    const float* __restrict__ src, const void* __restrict__ g,
    const void* __restrict__ bb, size_t goff,
    float* __restrict__ dst, const int* __restrict__ dtf)
{
    int isf32 = dtf[0];
    int t = blockIdx.x;
    const float* x = src + (size_t)t * HID;
    float* y = dst + (size_t)t * HID;
    int tid = threadIdx.x, lane = tid & 63, wave = tid >> 6;
    float v0 = x[tid], v1 = x[tid + 256];
    float s = v0 + v1;
    for (int off = 32; off; off >>= 1) s += __shfl_down(s, off, 64);
    __shared__ float wsum[4];
    if (lane == 0) wsum[wave] = s;
    __syncthreads();
    float mu = (wsum[0] + wsum[1] + wsum[2] + wsum[3]) * (1.f / 512.f);
    float d0 = v0 - mu, d1 = v1 - mu;
    float q = d0 * d0 + d1 * d1;
    for (int off = 32; off; off >>= 1) q += __shfl_down(q, off, 64);
    __syncthreads();
    if (lane == 0) wsum[wave] = q;
    __syncthreads();
    float var = (wsum[0] + wsum[1] + wsum[2] + wsum[3]) * (1.f / 512.f);
    float rstd = 1.f / sqrtf(var + 1e-5f);
    y[tid]       = d0 * rstd * ldin(g, goff + tid, isf32)       + ldin(bb, goff + tid, isf32);
    y[tid + 256] = d1 * rstd * ldin(g, goff + tid + 256, isf32) + ldin(bb, goff + tid + 256, isf32);
}

__global__ __launch_bounds__(128) void out_gemm_kernel(
    const float* __restrict__ x,
    const void* __restrict__ Wl, const void* __restrict__ bl,
    const void* __restrict__ Wr, const void* __restrict__ br,
    void* __restrict__ out, const int* __restrict__ dtf)
{
    int isf32 = dtf[0];
    int blk = blockIdx.x;
    int hand = blk >> 10;
    int bl_ = blk & 1023;
    int b = bl_ >> 6, l = bl_ & 63;
    const void* W = hand ? Wr : Wl;
    const void* bias = hand ? br : bl;
    int tok = b * S_ + 2 * l + hand;
    const float* xr = x + (size_t)tok * HID;
    int c = threadIdx.x;
    if (c < HANDD) {
        float acc = ldin(bias, c, isf32);
        #pragma unroll 8
        for (int k = 0; k < HID; k++) acc += xr[k] * ldin(W, (size_t)k * HANDD + c, isf32);
        size_t oi = (size_t)hand * (B_ * L_ * HANDD) + (size_t)bl_ * HANDD + c;
        if (isf32) ((float*)out)[oi] = acc;
        else       ((bf16*)out)[oi]  = __float2bfloat16(acc);
    }
}

extern "C" void kernel_launch(void* const* d_in, const int* in_sizes, int n_in,
                              void* d_out, int out_size, void* d_ws, size_t ws_size,
                              hipStream_t stream)
{
    const void* x_lhand = d_in[0];
    const void* x_rhand = d_in[1];
    const void* j_lhand = d_in[2];
    const void* j_rhand = d_in[3];
    const void* m_contact = d_in[4];
    const void* x_obj = d_in[5];
    const void* point_cloud = d_in[6];
    const void* fc_lw = d_in[7];
    const void* fc_lb = d_in[8];
    const void* fc_rw = d_in[9];
    const void* fc_rb = d_in[10];
    const void* out_lw = d_in[11];
    const void* out_lb = d_in[12];
    const void* out_rw = d_in[13];
    const void* out_rb = d_in[14];
    const void* Wqkv = d_in[15];
    const void* bqkv = d_in[16];
    const void* Wo   = d_in[17];
    const void* bo   = d_in[18];
    const void* W1   = d_in[19];
    const void* b1f  = d_in[20];
    const void* W2   = d_in[21];
    const void* b2fp = d_in[22];
    const void* ln1g = d_in[23];
    const void* ln1b = d_in[24];
    const void* ln2g = d_in[25];
    const void* ln2b = d_in[26];

    float* ws = (float*)d_ws;
    int* dtf = (int*)d_ws;
    float* x     = ws + F_X;
    float* pc_t  = ws + F_PCT;
    float* pcn   = ws + F_PCN;
    float* cat_l = ws + F_CATL;
    float* cat_r = ws + F_CATR;
    float* qkv   = ws + F_QKV;
    float* probs = ws + F_PROBS;
    float* ao    = ws + F_AO;
    float* tmp   = ws + F_TMP;
    float* h     = ws + F_H;
    float* ff    = ws + F_FF;
    unsigned short* wb = (unsigned short*)(ws + WB_F);

    detect_kernel<<<1, 256, 0, stream>>>(m_contact, dtf);

    // weight transposes (bf16 [N][Kpad])
    wtrans_kernel<<<dim3(8, 36, 1), 256, 0, stream>>>(fc_lw, 0, CATD, HID, CATP, wb + W_FCL, 0, dtf);
    wtrans_kernel<<<dim3(8, 36, 1), 256, 0, stream>>>(fc_rw, 0, CATD, HID, CATP, wb + W_FCR, 0, dtf);
    wtrans_kernel<<<dim3(24, 8, NLAY), 256, 0, stream>>>(Wqkv, (size_t)HID*1536, HID, 1536, HID, wb + W_QKV, (size_t)1536*HID, dtf);
    wtrans_kernel<<<dim3(8, 8, NLAY), 256, 0, stream>>>(Wo, (size_t)HID*HID, HID, HID, HID, wb + W_WO, (size_t)HID*HID, dtf);
    wtrans_kernel<<<dim3(32, 8, NLAY), 256, 0, stream>>>(W1, (size_t)HID*2048, HID, 2048, HID, wb + W_W1, (size_t)2048*HID, dtf);
    wtrans_kernel<<<dim3(8, 32, NLAY), 256, 0, stream>>>(W2, (size_t)2048*HID, 2048, HID, 2048, wb + W_W2, (size_t)HID*2048, dtf);

    pct_kernel<<<B_ * L_, 256, 0, stream>>>(x_obj, point_cloud, pc_t, pcn, dtf);
    build_cat_kernel<<<dim3(B_ * L_, 2), 256, 0, stream>>>(
        x_lhand, j_lhand, x_rhand, j_rhand, m_contact, pc_t, pcn, cat_l, cat_r, dtf);

    // fc projections -> interleaved x, PE fused in epilogue
    gemm_mfma<<<dim3(4, 8), 256, 0, stream>>>(cat_l, CATP, wb, W_FCL, HID, fc_lb, 0, nullptr, x, 0, 1, dtf);
    gemm_mfma<<<dim3(4, 8), 256, 0, stream>>>(cat_r, CATP, wb, W_FCR, HID, fc_rb, 0, nullptr, x, 0, 2, dtf);

    for (int i = 0; i < NLAY; i++) {
        size_t oWq = (size_t)W_QKV + (size_t)i * 1536 * HID, obq = (size_t)i * 1536;
        size_t oWo = (size_t)W_WO + (size_t)i * HID * HID,   obo = (size_t)i * HID;
        size_t oW1 = (size_t)W_W1 + (size_t)i * 2048 * HID,  ob1 = (size_t)i * 2048;
        size_t oW2 = (size_t)W_W2 + (size_t)i * HID * 2048,  ob2 = (size_t)i * HID;
        size_t oln = (size_t)i * HID;

        gemm_mfma<<<dim3(12, 16), 256, 0, stream>>>(x, HID, wb, oWq, 1536, bqkv, obq, nullptr, qkv, 0, 0, dtf);

        attn_scores_kernel<<<dim3(B_ * NHEAD, 4), 256, 0, stream>>>(qkv, probs);
        attn_av_kernel<<<dim3(B_ * NHEAD, 4), 256, 0, stream>>>(qkv, probs, ao);

        gemm_mfma<<<dim3(4, 16), 256, 0, stream>>>(ao, HID, wb, oWo, HID, bo, obo, x, tmp, 0, 0, dtf);
        ln_kernel<<<T_, 256, 0, stream>>>(tmp, ln1g, ln1b, oln, h, dtf);

        gemm_mfma<<<dim3(16, 16), 256, 0, stream>>>(h, HID, wb, oW1, 2048, b1f, ob1, nullptr, ff, 1, 0, dtf);
        gemm_mfma<<<dim3(4, 16), 256, 0, stream>>>(ff, 2048, wb, oW2, HID, b2fp, ob2, h, tmp, 0, 0, dtf);
        ln_kernel<<<T_, 256, 0, stream>>>(tmp, ln2g, ln2b, oln, x, dtf);
    }

    out_gemm_kernel<<<2 * B_ * L_, 128, 0, stream>>>(
        x, out_lw, out_lb, out_rw, out_rb, d_out, dtf);
}

// Round 7
// 1516.021 us; speedup vs baseline: 2.5823x; 1.0110x over previous
//
#include <hip/hip_runtime.h>
#include <hip/hip_bf16.h>

typedef __hip_bfloat16 bf16;
typedef __attribute__((ext_vector_type(8))) short short8;
typedef __attribute__((ext_vector_type(4))) float floatx4;

#define B_    16
#define L_    64
#define N_    1024
#define HANDD 99
#define Jn    21
#define HID   512
#define NLAY  4
#define NHEAD 8
#define DHEAD 64
#define CATD  2273
#define CATP  2304
#define S_    128
#define T_    2048

// float workspace offsets
#define F_X     16
#define F_QKV   1048592
#define F_PROBS 4194320
#define F_TMP   6291472
#define F_H     7340048
// phase-A aliases (dead before transformer layers run)
#define F_PCT   1048592
#define F_PCN   4194320
#define WB_F    8388624
// ushort offsets from wb
#define W_FCL   0
#define W_FCR   1179648
#define W_QKV   2359296
#define W_WO    5505024
#define W_W1    6553600
#define W_W2    10747904
#define U_CATL  14942208
#define U_CATR  17301504
#define U_XB    19660800
#define U_AOB   20709376
#define U_HB    21757952
#define U_FFB   U_CATL   // alias: cat buffers dead after fc

static __device__ __forceinline__ float b2f(bf16 x) { return __bfloat162float(x); }
static __device__ __forceinline__ float ldin(const void* p, size_t i, int isf32) {
    return isf32 ? ((const float*)p)[i] : b2f(((const bf16*)p)[i]);
}
static __device__ __forceinline__ unsigned short f2bf(float f) {
    unsigned int u = __float_as_uint(f);
    unsigned int r = (u + 0x7fffu + ((u >> 16) & 1u)) >> 16;
    return (unsigned short)r;
}

__global__ __launch_bounds__(256) void detect_kernel(const void* mc, int* flag)
{
    __shared__ int sbad;
    int tid = threadIdx.x;
    if (tid == 0) sbad = 0;
    __syncthreads();
    int bad = 0;
    for (int i = tid; i < 16384; i += 256) {
        float v = b2f(((const bf16*)mc)[i]);
        if (!(v >= -0.02f && v <= 1.02f)) bad = 1;
    }
    if (bad) atomicOr(&sbad, 1);
    __syncthreads();
    if (tid == 0) flag[0] = sbad ? 1 : 0;
}

// weight transpose+convert: src [K][N] -> dst [N][Kpad] bf16, zero pad
__global__ __launch_bounds__(256) void wtrans_kernel(
    const void* __restrict__ src, size_t src_layer, int K, int Nn, int Kpad,
    unsigned short* __restrict__ dst, size_t dst_layer, const int* __restrict__ dtf)
{
    int isf32 = dtf[0];
    __shared__ float tile[64][65];
    int lay = blockIdx.z;
    size_t soff = (size_t)lay * src_layer;
    size_t doff = (size_t)lay * dst_layer;
    int n0 = blockIdx.x * 64, k0 = blockIdx.y * 64;
    int a = threadIdx.x & 63, bq = threadIdx.x >> 6;
    for (int r = bq; r < 64; r += 4) {
        int k = k0 + r;
        float v = (k < K) ? ldin(src, soff + (size_t)k * Nn + (n0 + a), isf32) : 0.f;
        tile[r][a] = v;
    }
    __syncthreads();
    for (int r = bq; r < 64; r += 4) {
        dst[doff + (size_t)(n0 + r) * Kpad + k0 + a] = f2bf(tile[a][r]);
    }
}

__global__ __launch_bounds__(256) void pct_kernel(
    const void* __restrict__ x_obj, const void* __restrict__ pc,
    float* __restrict__ pc_t, float* __restrict__ pcn, const int* __restrict__ dtf)
{
    int isf32 = dtf[0];
    int bl = blockIdx.x;
    int b  = bl >> 6;
    size_t xo = (size_t)bl * 10;
    float t0 = ldin(x_obj, xo+0, isf32), t1 = ldin(x_obj, xo+1, isf32), t2 = ldin(x_obj, xo+2, isf32);
    float a1x = ldin(x_obj, xo+3, isf32), a1y = ldin(x_obj, xo+4, isf32), a1z = ldin(x_obj, xo+5, isf32);
    float a2x = ldin(x_obj, xo+6, isf32), a2y = ldin(x_obj, xo+7, isf32), a2z = ldin(x_obj, xo+8, isf32);
    float n1 = sqrtf(a1x*a1x + a1y*a1y + a1z*a1z);
    float b1x = a1x / n1, b1y = a1y / n1, b1z = a1z / n1;
    float d = b1x*a2x + b1y*a2y + b1z*a2z;
    float c2x = a2x - d*b1x, c2y = a2y - d*b1y, c2z = a2z - d*b1z;
    float n2 = sqrtf(c2x*c2x + c2y*c2y + c2z*c2z);
    float b2x = c2x / n2, b2y = c2y / n2, b2z = c2z / n2;
    float b3x = b1y*b2z - b1z*b2y;
    float b3y = b1z*b2x - b1x*b2z;
    float b3z = b1x*b2y - b1y*b2x;
    size_t pcb = (size_t)b * N_ * 3;
    float* outp = pc_t + (size_t)bl * N_ * 3;
    float* outn = pcn  + (size_t)bl * N_;
    for (int n = threadIdx.x; n < N_; n += 256) {
        float p0 = ldin(pc, pcb + n*3+0, isf32);
        float p1 = ldin(pc, pcb + n*3+1, isf32);
        float p2 = ldin(pc, pcb + n*3+2, isf32);
        float q0 = b1x*p0 + b2x*p1 + b3x*p2 + t0;
        float q1 = b1y*p0 + b2y*p1 + b3y*p2 + t1;
        float q2 = b1z*p0 + b2z*p1 + b3z*p2 + t2;
        outp[n*3+0] = q0; outp[n*3+1] = q1; outp[n*3+2] = q2;
        outn[n] = sqrtf(q0*q0 + q1*q1 + q2*q2);
    }
}

// feature row -> bf16: [x_hand 99 | j 63 | mc 1024 | pcn 1024 | att 63 | 0-pad]
__global__ __launch_bounds__(256) void build_cat_kernel(
    const void* __restrict__ x_l, const void* __restrict__ j_l,
    const void* __restrict__ x_r, const void* __restrict__ j_r,
    const void* __restrict__ mc, const float* __restrict__ pc_t,
    const float* __restrict__ pcn, unsigned short* __restrict__ cat_l,
    unsigned short* __restrict__ cat_r, const int* __restrict__ dtf)
{
    int isf32 = dtf[0];
    int hand = blockIdx.y;
    const void* x_hand = hand ? x_r : x_l;
    const void* j_hand = hand ? j_r : j_l;
    unsigned short* cat = hand ? cat_r : cat_l;
    int bl = blockIdx.x;
    int b  = bl >> 6;
    int tid = threadIdx.x;
    unsigned short* row = cat + (size_t)bl * CATP;
    const float* pct = pc_t + (size_t)bl * N_ * 3;

    for (int c = tid; c < HANDD; c += 256)  row[c]        = f2bf(ldin(x_hand, (size_t)bl*HANDD + c, isf32));
    for (int c = tid; c < 63;    c += 256)  row[99 + c]   = f2bf(ldin(j_hand, (size_t)bl*63 + c, isf32));
    for (int c = tid; c < N_;    c += 256)  row[162 + c]  = f2bf(ldin(mc, (size_t)b*N_ + c, isf32));
    for (int c = tid; c < N_;    c += 256)  row[1186 + c] = f2bf(pcn[(size_t)bl*N_ + c]);
    for (int c = CATD + tid; c < CATP; c += 256) row[c] = 0;

    int wave = tid >> 6, lane = tid & 63;
    for (int j = wave; j < Jn; j += 4) {
        float jx = ldin(j_hand, (size_t)bl*63 + j*3 + 0, isf32);
        float jy = ldin(j_hand, (size_t)bl*63 + j*3 + 1, isf32);
        float jz = ldin(j_hand, (size_t)bl*63 + j*3 + 2, isf32);
        float jj = jx*jx + jy*jy + jz*jz;
        float best = 3.4e38f; int bidx = 0x7fffffff;
        for (int n = lane; n < N_; n += 64) {
            float p0 = pct[n*3+0], p1 = pct[n*3+1], p2 = pct[n*3+2];
            float d2 = jj + (p0*p0 + p1*p1 + p2*p2) - 2.f*(jx*p0 + jy*p1 + jz*p2);
            if (d2 < best) { best = d2; bidx = n; }
        }
        for (int off = 32; off; off >>= 1) {
            float ob = __shfl_down(best, off, 64);
            int   oi = __shfl_down(bidx, off, 64);
            if (ob < best || (ob == best && oi < bidx)) { best = ob; bidx = oi; }
        }
        bidx = __shfl(bidx, 0, 64);
        if (lane < 3) {
            float jc = (lane == 0) ? jx : ((lane == 1) ? jy : jz);
            float cc = pct[bidx*3 + lane];
            float dd = jc - cc;
            row[2210 + j*3 + lane] = f2bf(expf(-50.f * dd * dd));
        }
    }
}

// Barrier-free direct-MFMA GEMM: each WAVE computes a 64x64 tile of
// D = A(bf16 [M][K]) @ Wt(bf16 [N][K])^T, fragments loaded straight from
// global (no LDS, no __syncthreads). Unroll-by-2 register ping-pong.
// Optional f32 out Df, bf16 out Db. rowmap 1/2: fc scatter + fused PE.
__global__ __launch_bounds__(256) void gemm_dw(
    const unsigned short* __restrict__ Ab, int K,
    const unsigned short* __restrict__ Wt, size_t wtoff, int Nn,
    const void* __restrict__ bias, size_t boff,
    const float* __restrict__ resid,
    float* __restrict__ Df, unsigned short* __restrict__ Db,
    int relu, int rowmap, int tilesN, const int* __restrict__ dtf)
{
    int gw = (blockIdx.x << 2) | (threadIdx.x >> 6);
    int lane = threadIdx.x & 63;
    int quad = lane >> 4, l16 = lane & 15;
    int tm = gw / tilesN, tn = gw - tm * tilesN;
    int row0 = tm << 6, col0 = tn << 6;

    const unsigned short* Ap = Ab + (size_t)(row0 + l16) * K + quad * 8;
    const unsigned short* Bp = Wt + wtoff + (size_t)(col0 + l16) * K + quad * 8;
    size_t astep = (size_t)16 * K;

    floatx4 acc[4][4];
    #pragma unroll
    for (int i = 0; i < 4; i++)
        #pragma unroll
        for (int j = 0; j < 4; j++)
            acc[i][j] = (floatx4){0.f, 0.f, 0.f, 0.f};

    short8 a0[4], b0[4], a1[4], b1[4];
    #pragma unroll
    for (int i = 0; i < 4; i++) {
        a0[i] = *(const short8*)(Ap + i * astep);
        b0[i] = *(const short8*)(Bp + i * astep);
    }

    for (int k0 = 0; k0 < K; k0 += 64) {
        #pragma unroll
        for (int i = 0; i < 4; i++) {
            a1[i] = *(const short8*)(Ap + i * astep + k0 + 32);
            b1[i] = *(const short8*)(Bp + i * astep + k0 + 32);
        }
        #pragma unroll
        for (int mi = 0; mi < 4; mi++)
            #pragma unroll
            for (int ni = 0; ni < 4; ni++)
                acc[mi][ni] = __builtin_amdgcn_mfma_f32_16x16x32_bf16(
                    a0[mi], b0[ni], acc[mi][ni], 0, 0, 0);
        int kn = k0 + 64;
        if (kn < K) {
            #pragma unroll
            for (int i = 0; i < 4; i++) {
                a0[i] = *(const short8*)(Ap + i * astep + kn);
                b0[i] = *(const short8*)(Bp + i * astep + kn);
            }
        }
        #pragma unroll
        for (int mi = 0; mi < 4; mi++)
            #pragma unroll
            for (int ni = 0; ni < 4; ni++)
                acc[mi][ni] = __builtin_amdgcn_mfma_f32_16x16x32_bf16(
                    a1[mi], b1[ni], acc[mi][ni], 0, 0, 0);
    }

    int isf32 = dtf[0];
    #pragma unroll
    for (int ni = 0; ni < 4; ni++) {
        int c = col0 + ni * 16 + l16;
        float bv = bias ? ldin(bias, boff + c, isf32) : 0.f;
        float pe_div = 0.f, pa = 0.f;
        if (rowmap) {
            int ci = c & ~1;
            pe_div = expf((float)ci * (-logf(10000.f) / (float)HID));
            int hand = rowmap - 1;
            pa = (c & 1) ? cosf((float)hand * pe_div) : sinf((float)hand * pe_div);
        }
        #pragma unroll
        for (int mi = 0; mi < 4; mi++) {
            #pragma unroll
            for (int reg = 0; reg < 4; reg++) {
                int r = row0 + mi * 16 + quad * 4 + reg;
                float v = acc[mi][ni][reg] + bv;
                if (resid) v += resid[(size_t)r * Nn + c];
                if (relu)  v = fmaxf(v, 0.f);
                int orow = r;
                if (rowmap) {
                    int bb = r >> 6, ll = r & 63;
                    orow = bb * S_ + 2 * ll + (rowmap - 1);
                    float pf = (c & 1) ? cosf((float)ll * pe_div) : sinf((float)ll * pe_div);
                    v += pf + pa;
                }
                if (Df) Df[(size_t)orow * Nn + c] = v;
                if (Db) Db[(size_t)orow * Nn + c] = f2bf(v);
            }
        }
    }
}

__global__ __launch_bounds__(256) void attn_scores_kernel(
    const float* __restrict__ qkv, float* __restrict__ probs)
{
    int bh = blockIdx.x;
    int b = bh >> 3, h = bh & 7;
    __shared__ float Ks[S_][DHEAD + 1];
    int tid = threadIdx.x;
    for (int i = tid; i < S_ * DHEAD; i += 256) {
        int r = i >> 6, dd = i & 63;
        Ks[r][dd] = qkv[(size_t)(b * S_ + r) * 1536 + 512 + h * DHEAD + dd];
    }
    __syncthreads();
    int wave = tid >> 6, lane = tid & 63;
    int rbase = blockIdx.y * 32;
    for (int r = rbase + wave; r < rbase + 32; r += 4) {
        const float* qrow = &qkv[(size_t)(b * S_ + r) * 1536 + h * DHEAD];
        float s0 = 0.f, s1 = 0.f;
        #pragma unroll 8
        for (int dd = 0; dd < DHEAD; dd++) {
            float qd = qrow[dd];
            s0 += qd * Ks[lane][dd];
            s1 += qd * Ks[lane + 64][dd];
        }
        s0 *= 0.125f; s1 *= 0.125f;
        float m = fmaxf(s0, s1);
        for (int off = 32; off; off >>= 1) m = fmaxf(m, __shfl_down(m, off, 64));
        m = __shfl(m, 0, 64);
        float e0 = expf(s0 - m), e1 = expf(s1 - m);
        float sum = e0 + e1;
        for (int off = 32; off; off >>= 1) sum += __shfl_down(sum, off, 64);
        sum = __shfl(sum, 0, 64);
        float inv = 1.f / sum;
        size_t base = ((size_t)bh * S_ + r) * S_;
        probs[base + lane]      = e0 * inv;
        probs[base + lane + 64] = e1 * inv;
    }
}

__global__ __launch_bounds__(256) void attn_av_kernel(
    const float* __restrict__ qkv, const float* __restrict__ probs,
    unsigned short* __restrict__ aob)
{
    int bh = blockIdx.x;
    int b = bh >> 3, h = bh & 7;
    __shared__ float Vs[S_][DHEAD + 1];
    int tid = threadIdx.x;
    for (int i = tid; i < S_ * DHEAD; i += 256) {
        int r = i >> 6, dd = i & 63;
        Vs[r][dd] = qkv[(size_t)(b * S_ + r) * 1536 + 1024 + h * DHEAD + dd];
    }
    __syncthreads();
    int wave = tid >> 6, lane = tid & 63;
    int rbase = blockIdx.y * 32;
    for (int r = rbase + wave; r < rbase + 32; r += 4) {
        const float* prow = &probs[((size_t)bh * S_ + r) * S_];
        float acc = 0.f;
        #pragma unroll 8
        for (int k = 0; k < S_; k++) acc += prow[k] * Vs[k][lane];
        aob[(size_t)(b * S_ + r) * HID + h * DHEAD + lane] = f2bf(acc);
    }
}

__global__ __launch_bounds__(256) void ln_kernel(
    const float* __restrict__ src, const void* __restrict__ g,
    const void* __restrict__ bb, size_t goff,
    float* __restrict__ dst, unsigned short* __restrict__ dstb,
    const int* __restrict__ dtf)
{
    int isf32 = dtf[0];
    int t = blockIdx.x;
    const float* x = src + (size_t)t * HID;
    int tid = threadIdx.x, lane = tid & 63, wave = tid >> 6;
    float v0 = x[tid], v1 = x[tid + 256];
    float s = v0 + v1;
    for (int off = 32; off; off >>= 1) s += __shfl_down(s, off, 64);
    __shared__ float wsum[4];
    if (lane == 0) wsum[wave] = s;
    __syncthreads();
    float mu = (wsum[0] + wsum[1] + wsum[2] + wsum[3]) * (1.f / 512.f);
    float d0 = v0 - mu, d1 = v1 - mu;
    float q = d0 * d0 + d1 * d1;
    for (int off = 32; off; off >>= 1) q += __shfl_down(q, off, 64);
    __syncthreads();
    if (lane == 0) wsum[wave] = q;
    __syncthreads();
    float var = (wsum[0] + wsum[1] + wsum[2] + wsum[3]) * (1.f / 512.f);
    float rstd = 1.f / sqrtf(var + 1e-5f);
    float y0 = d0 * rstd * ldin(g, goff + tid, isf32)       + ldin(bb, goff + tid, isf32);
    float y1 = d1 * rstd * ldin(g, goff + tid + 256, isf32) + ldin(bb, goff + tid + 256, isf32);
    if (dst) {
        dst[(size_t)t * HID + tid]       = y0;
        dst[(size_t)t * HID + tid + 256] = y1;
    }
    if (dstb) {
        dstb[(size_t)t * HID + tid]       = f2bf(y0);
        dstb[(size_t)t * HID + tid + 256] = f2bf(y1);
    }
}

__global__ __launch_bounds__(128) void out_gemm_kernel(
    const float* __restrict__ x,
    const void* __restrict__ Wl, const void* __restrict__ bl,
    const void* __restrict__ Wr, const void* __restrict__ br,
    void* __restrict__ out, const int* __restrict__ dtf)
{
    int isf32 = dtf[0];
    int blk = blockIdx.x;
    int hand = blk >> 10;
    int bl_ = blk & 1023;
    int b = bl_ >> 6, l = bl_ & 63;
    const void* W = hand ? Wr : Wl;
    const void* bias = hand ? br : bl;
    int tok = b * S_ + 2 * l + hand;
    const float* xr = x + (size_t)tok * HID;
    int c = threadIdx.x;
    if (c < HANDD) {
        float acc = ldin(bias, c, isf32);
        #pragma unroll 8
        for (int k = 0; k < HID; k++) acc += xr[k] * ldin(W, (size_t)k * HANDD + c, isf32);
        size_t oi = (size_t)hand * (B_ * L_ * HANDD) + (size_t)bl_ * HANDD + c;
        if (isf32) ((float*)out)[oi] = acc;
        else       ((bf16*)out)[oi]  = __float2bfloat16(acc);
    }
}

extern "C" void kernel_launch(void* const* d_in, const int* in_sizes, int n_in,
                              void* d_out, int out_size, void* d_ws, size_t ws_size,
                              hipStream_t stream)
{
    const void* x_lhand = d_in[0];
    const void* x_rhand = d_in[1];
    const void* j_lhand = d_in[2];
    const void* j_rhand = d_in[3];
    const void* m_contact = d_in[4];
    const void* x_obj = d_in[5];
    const void* point_cloud = d_in[6];
    const void* fc_lw = d_in[7];
    const void* fc_lb = d_in[8];
    const void* fc_rw = d_in[9];
    const void* fc_rb = d_in[10];
    const void* out_lw = d_in[11];
    const void* out_lb = d_in[12];
    const void* out_rw = d_in[13];
    const void* out_rb = d_in[14];
    const void* Wqkv = d_in[15];
    const void* bqkv = d_in[16];
    const void* Wo   = d_in[17];
    const void* bo   = d_in[18];
    const void* W1   = d_in[19];
    const void* b1f  = d_in[20];
    const void* W2   = d_in[21];
    const void* b2fp = d_in[22];
    const void* ln1g = d_in[23];
    const void* ln1b = d_in[24];
    const void* ln2g = d_in[25];
    const void* ln2b = d_in[26];

    float* ws = (float*)d_ws;
    int* dtf = (int*)d_ws;
    float* x     = ws + F_X;
    float* qkv   = ws + F_QKV;
    float* probs = ws + F_PROBS;
    float* tmp   = ws + F_TMP;
    float* h     = ws + F_H;
    float* pc_t  = ws + F_PCT;
    float* pcn   = ws + F_PCN;
    unsigned short* wb   = (unsigned short*)(ws + WB_F);
    unsigned short* catl = wb + U_CATL;
    unsigned short* catr = wb + U_CATR;
    unsigned short* xb   = wb + U_XB;
    unsigned short* aob  = wb + U_AOB;
    unsigned short* hb   = wb + U_HB;
    unsigned short* ffb  = wb + U_FFB;

    detect_kernel<<<1, 256, 0, stream>>>(m_contact, dtf);

    wtrans_kernel<<<dim3(8, 36, 1), 256, 0, stream>>>(fc_lw, 0, CATD, HID, CATP, wb + W_FCL, 0, dtf);
    wtrans_kernel<<<dim3(8, 36, 1), 256, 0, stream>>>(fc_rw, 0, CATD, HID, CATP, wb + W_FCR, 0, dtf);
    wtrans_kernel<<<dim3(24, 8, NLAY), 256, 0, stream>>>(Wqkv, (size_t)HID*1536, HID, 1536, HID, wb + W_QKV, (size_t)1536*HID, dtf);
    wtrans_kernel<<<dim3(8, 8, NLAY), 256, 0, stream>>>(Wo, (size_t)HID*HID, HID, HID, HID, wb + W_WO, (size_t)HID*HID, dtf);
    wtrans_kernel<<<dim3(32, 8, NLAY), 256, 0, stream>>>(W1, (size_t)HID*2048, HID, 2048, HID, wb + W_W1, (size_t)2048*HID, dtf);
    wtrans_kernel<<<dim3(8, 32, NLAY), 256, 0, stream>>>(W2, (size_t)2048*HID, 2048, HID, 2048, wb + W_W2, (size_t)HID*2048, dtf);

    pct_kernel<<<B_ * L_, 256, 0, stream>>>(x_obj, point_cloud, pc_t, pcn, dtf);
    build_cat_kernel<<<dim3(B_ * L_, 2), 256, 0, stream>>>(
        x_lhand, j_lhand, x_rhand, j_rhand, m_contact, pc_t, pcn, catl, catr, dtf);

    // fc: M=1024,K=2304,N=512 -> 16x8=128 tiles -> 32 blocks; PE fused
    gemm_dw<<<32, 256, 0, stream>>>(catl, CATP, wb, W_FCL, HID, fc_lb, 0, nullptr, x, xb, 0, 1, 8, dtf);
    gemm_dw<<<32, 256, 0, stream>>>(catr, CATP, wb, W_FCR, HID, fc_rb, 0, nullptr, x, xb, 0, 2, 8, dtf);

    for (int i = 0; i < NLAY; i++) {
        size_t oWq = (size_t)W_QKV + (size_t)i * 1536 * HID, obq = (size_t)i * 1536;
        size_t oWo = (size_t)W_WO + (size_t)i * HID * HID,   obo = (size_t)i * HID;
        size_t oW1 = (size_t)W_W1 + (size_t)i * 2048 * HID,  ob1 = (size_t)i * 2048;
        size_t oW2 = (size_t)W_W2 + (size_t)i * HID * 2048,  ob2 = (size_t)i * HID;
        size_t oln = (size_t)i * HID;

        // qkv: 32x24=768 tiles -> 192 blocks
        gemm_dw<<<192, 256, 0, stream>>>(xb, HID, wb, oWq, 1536, bqkv, obq, nullptr, qkv, nullptr, 0, 0, 24, dtf);

        attn_scores_kernel<<<dim3(B_ * NHEAD, 4), 256, 0, stream>>>(qkv, probs);
        attn_av_kernel<<<dim3(B_ * NHEAD, 4), 256, 0, stream>>>(qkv, probs, aob);

        // Wo: 32x8=256 tiles -> 64 blocks
        gemm_dw<<<64, 256, 0, stream>>>(aob, HID, wb, oWo, HID, bo, obo, x, tmp, nullptr, 0, 0, 8, dtf);
        ln_kernel<<<T_, 256, 0, stream>>>(tmp, ln1g, ln1b, oln, h, hb, dtf);

        // W1: 32x32=1024 tiles -> 256 blocks (relu, bf16 out only)
        gemm_dw<<<256, 256, 0, stream>>>(hb, HID, wb, oW1, 2048, b1f, ob1, nullptr, nullptr, ffb, 1, 0, 32, dtf);
        // W2: K=2048, 32x8=256 tiles -> 64 blocks
        gemm_dw<<<64, 256, 0, stream>>>(ffb, 2048, wb, oW2, HID, b2fp, ob2, h, tmp, nullptr, 0, 0, 8, dtf);
        ln_kernel<<<T_, 256, 0, stream>>>(tmp, ln2g, ln2b, oln, x, xb, dtf);
    }

    out_gemm_kernel<<<2 * B_ * L_, 128, 0, stream>>>(
        x, out_lw, out_lb, out_rw, out_rb, d_out, dtf);
}

// Round 8
// 922.706 us; speedup vs baseline: 4.2427x; 1.6430x over previous
//
#include <hip/hip_runtime.h>
#include <hip/hip_bf16.h>

typedef __hip_bfloat16 bf16;
typedef __attribute__((ext_vector_type(8))) short short8;
typedef __attribute__((ext_vector_type(4))) float floatx4;

#define B_    16
#define L_    64
#define N_    1024
#define HANDD 99
#define Jn    21
#define HID   512
#define NLAY  4
#define NHEAD 8
#define DHEAD 64
#define CATD  2273
#define CATP  2304
#define S_    128
#define T_    2048

// float workspace offsets
#define F_X     16
#define F_QKV   1048592
#define F_PROBS 4194320
#define F_TMP   6291472
#define F_H     7340048
// phase-A aliases (dead before transformer layers run)
#define F_PCT   1048592
#define F_PCN   4194320
#define WB_F    8388624
// ushort offsets from wb
#define W_FCL   0
#define W_FCR   1179648
#define W_QKV   2359296
#define W_WO    5505024
#define W_W1    6553600
#define W_W2    10747904
#define U_CATL  14942208
#define U_CATR  17301504
#define U_XB    19660800
#define U_AOB   20709376
#define U_HB    21757952
#define U_FFB   U_CATL   // alias: cat buffers dead after fc

static __device__ __forceinline__ float b2f(bf16 x) { return __bfloat162float(x); }
static __device__ __forceinline__ float ldin(const void* p, size_t i, int isf32) {
    return isf32 ? ((const float*)p)[i] : b2f(((const bf16*)p)[i]);
}
static __device__ __forceinline__ unsigned short f2bf(float f) {
    unsigned int u = __float_as_uint(f);
    unsigned int r = (u + 0x7fffu + ((u >> 16) & 1u)) >> 16;
    return (unsigned short)r;
}

__global__ __launch_bounds__(256) void detect_kernel(const void* mc, int* flag)
{
    __shared__ int sbad;
    int tid = threadIdx.x;
    if (tid == 0) sbad = 0;
    __syncthreads();
    int bad = 0;
    for (int i = tid; i < 16384; i += 256) {
        float v = b2f(((const bf16*)mc)[i]);
        if (!(v >= -0.02f && v <= 1.02f)) bad = 1;
    }
    if (bad) atomicOr(&sbad, 1);
    __syncthreads();
    if (tid == 0) flag[0] = sbad ? 1 : 0;
}

// weight transpose+convert: src [K][N] -> dst [N][Kpad] bf16, zero pad
__global__ __launch_bounds__(256) void wtrans_kernel(
    const void* __restrict__ src, size_t src_layer, int K, int Nn, int Kpad,
    unsigned short* __restrict__ dst, size_t dst_layer, const int* __restrict__ dtf)
{
    int isf32 = dtf[0];
    __shared__ float tile[64][65];
    int lay = blockIdx.z;
    size_t soff = (size_t)lay * src_layer;
    size_t doff = (size_t)lay * dst_layer;
    int n0 = blockIdx.x * 64, k0 = blockIdx.y * 64;
    int a = threadIdx.x & 63, bq = threadIdx.x >> 6;
    for (int r = bq; r < 64; r += 4) {
        int k = k0 + r;
        float v = (k < K) ? ldin(src, soff + (size_t)k * Nn + (n0 + a), isf32) : 0.f;
        tile[r][a] = v;
    }
    __syncthreads();
    for (int r = bq; r < 64; r += 4) {
        dst[doff + (size_t)(n0 + r) * Kpad + k0 + a] = f2bf(tile[a][r]);
    }
}

__global__ __launch_bounds__(256) void pct_kernel(
    const void* __restrict__ x_obj, const void* __restrict__ pc,
    float* __restrict__ pc_t, float* __restrict__ pcn, const int* __restrict__ dtf)
{
    int isf32 = dtf[0];
    int bl = blockIdx.x;
    int b  = bl >> 6;
    size_t xo = (size_t)bl * 10;
    float t0 = ldin(x_obj, xo+0, isf32), t1 = ldin(x_obj, xo+1, isf32), t2 = ldin(x_obj, xo+2, isf32);
    float a1x = ldin(x_obj, xo+3, isf32), a1y = ldin(x_obj, xo+4, isf32), a1z = ldin(x_obj, xo+5, isf32);
    float a2x = ldin(x_obj, xo+6, isf32), a2y = ldin(x_obj, xo+7, isf32), a2z = ldin(x_obj, xo+8, isf32);
    float n1 = sqrtf(a1x*a1x + a1y*a1y + a1z*a1z);
    float b1x = a1x / n1, b1y = a1y / n1, b1z = a1z / n1;
    float d = b1x*a2x + b1y*a2y + b1z*a2z;
    float c2x = a2x - d*b1x, c2y = a2y - d*b1y, c2z = a2z - d*b1z;
    float n2 = sqrtf(c2x*c2x + c2y*c2y + c2z*c2z);
    float b2x = c2x / n2, b2y = c2y / n2, b2z = c2z / n2;
    float b3x = b1y*b2z - b1z*b2y;
    float b3y = b1z*b2x - b1x*b2z;
    float b3z = b1x*b2y - b1y*b2x;
    size_t pcb = (size_t)b * N_ * 3;
    float* outp = pc_t + (size_t)bl * N_ * 3;
    float* outn = pcn  + (size_t)bl * N_;
    for (int n = threadIdx.x; n < N_; n += 256) {
        float p0 = ldin(pc, pcb + n*3+0, isf32);
        float p1 = ldin(pc, pcb + n*3+1, isf32);
        float p2 = ldin(pc, pcb + n*3+2, isf32);
        float q0 = b1x*p0 + b2x*p1 + b3x*p2 + t0;
        float q1 = b1y*p0 + b2y*p1 + b3y*p2 + t1;
        float q2 = b1z*p0 + b2z*p1 + b3z*p2 + t2;
        outp[n*3+0] = q0; outp[n*3+1] = q1; outp[n*3+2] = q2;
        outn[n] = sqrtf(q0*q0 + q1*q1 + q2*q2);
    }
}

// feature row -> bf16: [x_hand 99 | j 63 | mc 1024 | pcn 1024 | att 63 | 0-pad]
__global__ __launch_bounds__(256) void build_cat_kernel(
    const void* __restrict__ x_l, const void* __restrict__ j_l,
    const void* __restrict__ x_r, const void* __restrict__ j_r,
    const void* __restrict__ mc, const float* __restrict__ pc_t,
    const float* __restrict__ pcn, unsigned short* __restrict__ cat_l,
    unsigned short* __restrict__ cat_r, const int* __restrict__ dtf)
{
    int isf32 = dtf[0];
    int hand = blockIdx.y;
    const void* x_hand = hand ? x_r : x_l;
    const void* j_hand = hand ? j_r : j_l;
    unsigned short* cat = hand ? cat_r : cat_l;
    int bl = blockIdx.x;
    int b  = bl >> 6;
    int tid = threadIdx.x;
    unsigned short* row = cat + (size_t)bl * CATP;
    const float* pct = pc_t + (size_t)bl * N_ * 3;

    for (int c = tid; c < HANDD; c += 256)  row[c]        = f2bf(ldin(x_hand, (size_t)bl*HANDD + c, isf32));
    for (int c = tid; c < 63;    c += 256)  row[99 + c]   = f2bf(ldin(j_hand, (size_t)bl*63 + c, isf32));
    for (int c = tid; c < N_;    c += 256)  row[162 + c]  = f2bf(ldin(mc, (size_t)b*N_ + c, isf32));
    for (int c = tid; c < N_;    c += 256)  row[1186 + c] = f2bf(pcn[(size_t)bl*N_ + c]);
    for (int c = CATD + tid; c < CATP; c += 256) row[c] = 0;

    int wave = tid >> 6, lane = tid & 63;
    for (int j = wave; j < Jn; j += 4) {
        float jx = ldin(j_hand, (size_t)bl*63 + j*3 + 0, isf32);
        float jy = ldin(j_hand, (size_t)bl*63 + j*3 + 1, isf32);
        float jz = ldin(j_hand, (size_t)bl*63 + j*3 + 2, isf32);
        float jj = jx*jx + jy*jy + jz*jz;
        float best = 3.4e38f; int bidx = 0x7fffffff;
        for (int n = lane; n < N_; n += 64) {
            float p0 = pct[n*3+0], p1 = pct[n*3+1], p2 = pct[n*3+2];
            float d2 = jj + (p0*p0 + p1*p1 + p2*p2) - 2.f*(jx*p0 + jy*p1 + jz*p2);
            if (d2 < best) { best = d2; bidx = n; }
        }
        for (int off = 32; off; off >>= 1) {
            float ob = __shfl_down(best, off, 64);
            int   oi = __shfl_down(bidx, off, 64);
            if (ob < best || (ob == best && oi < bidx)) { best = ob; bidx = oi; }
        }
        bidx = __shfl(bidx, 0, 64);
        if (lane < 3) {
            float jc = (lane == 0) ? jx : ((lane == 1) ? jy : jz);
            float cc = pct[bidx*3 + lane];
            float dd = jc - cc;
            row[2210 + j*3 + lane] = f2bf(expf(-50.f * dd * dd));
        }
    }
}

// K-split MFMA GEMM: each block computes one 64x64 tile; its 4 waves each
// process K/4 (short dependent chain), partials reduced through LDS.
// D = A(bf16 [M][K]) @ Wt(bf16 [N][K])^T. rowmap 1/2: fc scatter + fused PE.
#define RSTR 68

__global__ __launch_bounds__(256) void gemm_ks(
    const unsigned short* __restrict__ Ab, int K,
    const unsigned short* __restrict__ Wt, size_t wtoff, int Nn,
    const void* __restrict__ bias, size_t boff,
    const float* __restrict__ resid,
    float* __restrict__ Df, unsigned short* __restrict__ Db,
    int relu, int rowmap, int tilesN, const int* __restrict__ dtf)
{
    __shared__ float red[4][64 * RSTR];
    int tid = threadIdx.x;
    int wave = tid >> 6, lane = tid & 63;
    int quad = lane >> 4, l16 = lane & 15;
    int tm = blockIdx.x / tilesN, tn = blockIdx.x - tm * tilesN;
    int row0 = tm << 6, col0 = tn << 6;
    int Ks = K >> 2;                 // K-slice per wave (K % 128 == 0 here)
    int ks0 = wave * Ks;

    const unsigned short* Ap = Ab + (size_t)(row0 + l16) * K + ks0 + quad * 8;
    const unsigned short* Bp = Wt + wtoff + (size_t)(col0 + l16) * K + ks0 + quad * 8;
    size_t astep = (size_t)16 * K;

    floatx4 acc[4][4];
    #pragma unroll
    for (int i = 0; i < 4; i++)
        #pragma unroll
        for (int j = 0; j < 4; j++)
            acc[i][j] = (floatx4){0.f, 0.f, 0.f, 0.f};

    for (int k = 0; k < Ks; k += 32) {
        short8 af[4], bf[4];
        #pragma unroll
        for (int i = 0; i < 4; i++) {
            af[i] = *(const short8*)(Ap + i * astep + k);
            bf[i] = *(const short8*)(Bp + i * astep + k);
        }
        #pragma unroll
        for (int mi = 0; mi < 4; mi++)
            #pragma unroll
            for (int ni = 0; ni < 4; ni++)
                acc[mi][ni] = __builtin_amdgcn_mfma_f32_16x16x32_bf16(
                    af[mi], bf[ni], acc[mi][ni], 0, 0, 0);
    }

    // write partials (2-way bank alias only)
    #pragma unroll
    for (int mi = 0; mi < 4; mi++)
        #pragma unroll
        for (int ni = 0; ni < 4; ni++)
            #pragma unroll
            for (int reg = 0; reg < 4; reg++) {
                int r = mi * 16 + quad * 4 + reg;
                int c = ni * 16 + l16;
                red[wave][r * RSTR + c] = acc[mi][ni][reg];
            }
    __syncthreads();

    int isf32 = dtf[0];
    int cc = tid & 63;
    int c = col0 + cc;
    float bv = bias ? ldin(bias, boff + c, isf32) : 0.f;
    float pe_div = 0.f, pa = 0.f;
    if (rowmap) {
        int ci = c & ~1;
        pe_div = expf((float)ci * (-logf(10000.f) / (float)HID));
        int hand = rowmap - 1;
        pa = (c & 1) ? cosf((float)hand * pe_div) : sinf((float)hand * pe_div);
    }
    int rbase = tid >> 6;
    #pragma unroll
    for (int j = 0; j < 16; j++) {
        int rr = rbase + (j << 2);
        int idx = rr * RSTR + cc;
        float v = red[0][idx] + red[1][idx] + red[2][idx] + red[3][idx] + bv;
        int r = row0 + rr;
        if (resid) v += resid[(size_t)r * Nn + c];
        if (relu)  v = fmaxf(v, 0.f);
        int orow = r;
        if (rowmap) {
            int bb = r >> 6, ll = r & 63;
            orow = bb * S_ + 2 * ll + (rowmap - 1);
            float pf = (c & 1) ? cosf((float)ll * pe_div) : sinf((float)ll * pe_div);
            v += pf + pa;
        }
        if (Df) Df[(size_t)orow * Nn + c] = v;
        if (Db) Db[(size_t)orow * Nn + c] = f2bf(v);
    }
}

__global__ __launch_bounds__(256) void attn_scores_kernel(
    const float* __restrict__ qkv, float* __restrict__ probs)
{
    int bh = blockIdx.x;
    int b = bh >> 3, h = bh & 7;
    __shared__ float Ks[S_][DHEAD + 1];
    int tid = threadIdx.x;
    for (int i = tid; i < S_ * DHEAD; i += 256) {
        int r = i >> 6, dd = i & 63;
        Ks[r][dd] = qkv[(size_t)(b * S_ + r) * 1536 + 512 + h * DHEAD + dd];
    }
    __syncthreads();
    int wave = tid >> 6, lane = tid & 63;
    int rbase = blockIdx.y * 32;
    for (int r = rbase + wave; r < rbase + 32; r += 4) {
        const float* qrow = &qkv[(size_t)(b * S_ + r) * 1536 + h * DHEAD];
        float s0 = 0.f, s1 = 0.f;
        #pragma unroll 8
        for (int dd = 0; dd < DHEAD; dd++) {
            float qd = qrow[dd];
            s0 += qd * Ks[lane][dd];
            s1 += qd * Ks[lane + 64][dd];
        }
        s0 *= 0.125f; s1 *= 0.125f;
        float m = fmaxf(s0, s1);
        for (int off = 32; off; off >>= 1) m = fmaxf(m, __shfl_down(m, off, 64));
        m = __shfl(m, 0, 64);
        float e0 = expf(s0 - m), e1 = expf(s1 - m);
        float sum = e0 + e1;
        for (int off = 32; off; off >>= 1) sum += __shfl_down(sum, off, 64);
        sum = __shfl(sum, 0, 64);
        float inv = 1.f / sum;
        size_t base = ((size_t)bh * S_ + r) * S_;
        probs[base + lane]      = e0 * inv;
        probs[base + lane + 64] = e1 * inv;
    }
}

__global__ __launch_bounds__(256) void attn_av_kernel(
    const float* __restrict__ qkv, const float* __restrict__ probs,
    unsigned short* __restrict__ aob)
{
    int bh = blockIdx.x;
    int b = bh >> 3, h = bh & 7;
    __shared__ float Vs[S_][DHEAD + 1];
    int tid = threadIdx.x;
    for (int i = tid; i < S_ * DHEAD; i += 256) {
        int r = i >> 6, dd = i & 63;
        Vs[r][dd] = qkv[(size_t)(b * S_ + r) * 1536 + 1024 + h * DHEAD + dd];
    }
    __syncthreads();
    int wave = tid >> 6, lane = tid & 63;
    int rbase = blockIdx.y * 32;
    for (int r = rbase + wave; r < rbase + 32; r += 4) {
        const float* prow = &probs[((size_t)bh * S_ + r) * S_];
        float acc = 0.f;
        #pragma unroll 8
        for (int k = 0; k < S_; k++) acc += prow[k] * Vs[k][lane];
        aob[(size_t)(b * S_ + r) * HID + h * DHEAD + lane] = f2bf(acc);
    }
}

__global__ __launch_bounds__(256) void ln_kernel(
    const float* __restrict__ src, const void* __restrict__ g,
    const void* __restrict__ bb, size_t goff,
    float* __restrict__ dst, unsigned short* __restrict__ dstb,
    const int* __restrict__ dtf)
{
    int isf32 = dtf[0];
    int t = blockIdx.x;
    const float* x = src + (size_t)t * HID;
    int tid = threadIdx.x, lane = tid & 63, wave = tid >> 6;
    float v0 = x[tid], v1 = x[tid + 256];
    float s = v0 + v1;
    for (int off = 32; off; off >>= 1) s += __shfl_down(s, off, 64);
    __shared__ float wsum[4];
    if (lane == 0) wsum[wave] = s;
    __syncthreads();
    float mu = (wsum[0] + wsum[1] + wsum[2] + wsum[3]) * (1.f / 512.f);
    float d0 = v0 - mu, d1 = v1 - mu;
    float q = d0 * d0 + d1 * d1;
    for (int off = 32; off; off >>= 1) q += __shfl_down(q, off, 64);
    __syncthreads();
    if (lane == 0) wsum[wave] = q;
    __syncthreads();
    float var = (wsum[0] + wsum[1] + wsum[2] + wsum[3]) * (1.f / 512.f);
    float rstd = 1.f / sqrtf(var + 1e-5f);
    float y0 = d0 * rstd * ldin(g, goff + tid, isf32)       + ldin(bb, goff + tid, isf32);
    float y1 = d1 * rstd * ldin(g, goff + tid + 256, isf32) + ldin(bb, goff + tid + 256, isf32);
    if (dst) {
        dst[(size_t)t * HID + tid]       = y0;
        dst[(size_t)t * HID + tid + 256] = y1;
    }
    if (dstb) {
        dstb[(size_t)t * HID + tid]       = f2bf(y0);
        dstb[(size_t)t * HID + tid + 256] = f2bf(y1);
    }
}

__global__ __launch_bounds__(128) void out_gemm_kernel(
    const float* __restrict__ x,
    const void* __restrict__ Wl, const void* __restrict__ bl,
    const void* __restrict__ Wr, const void* __restrict__ br,
    void* __restrict__ out, const int* __restrict__ dtf)
{
    int isf32 = dtf[0];
    int blk = blockIdx.x;
    int hand = blk >> 10;
    int bl_ = blk & 1023;
    int b = bl_ >> 6, l = bl_ & 63;
    const void* W = hand ? Wr : Wl;
    const void* bias = hand ? br : bl;
    int tok = b * S_ + 2 * l + hand;
    const float* xr = x + (size_t)tok * HID;
    int c = threadIdx.x;
    if (c < HANDD) {
        float acc = ldin(bias, c, isf32);
        #pragma unroll 8
        for (int k = 0; k < HID; k++) acc += xr[k] * ldin(W, (size_t)k * HANDD + c, isf32);
        size_t oi = (size_t)hand * (B_ * L_ * HANDD) + (size_t)bl_ * HANDD + c;
        if (isf32) ((float*)out)[oi] = acc;
        else       ((bf16*)out)[oi]  = __float2bfloat16(acc);
    }
}

extern "C" void kernel_launch(void* const* d_in, const int* in_sizes, int n_in,
                              void* d_out, int out_size, void* d_ws, size_t ws_size,
                              hipStream_t stream)
{
    const void* x_lhand = d_in[0];
    const void* x_rhand = d_in[1];
    const void* j_lhand = d_in[2];
    const void* j_rhand = d_in[3];
    const void* m_contact = d_in[4];
    const void* x_obj = d_in[5];
    const void* point_cloud = d_in[6];
    const void* fc_lw = d_in[7];
    const void* fc_lb = d_in[8];
    const void* fc_rw = d_in[9];
    const void* fc_rb = d_in[10];
    const void* out_lw = d_in[11];
    const void* out_lb = d_in[12];
    const void* out_rw = d_in[13];
    const void* out_rb = d_in[14];
    const void* Wqkv = d_in[15];
    const void* bqkv = d_in[16];
    const void* Wo   = d_in[17];
    const void* bo   = d_in[18];
    const void* W1   = d_in[19];
    const void* b1f  = d_in[20];
    const void* W2   = d_in[21];
    const void* b2fp = d_in[22];
    const void* ln1g = d_in[23];
    const void* ln1b = d_in[24];
    const void* ln2g = d_in[25];
    const void* ln2b = d_in[26];

    float* ws = (float*)d_ws;
    int* dtf = (int*)d_ws;
    float* x     = ws + F_X;
    float* qkv   = ws + F_QKV;
    float* probs = ws + F_PROBS;
    float* tmp   = ws + F_TMP;
    float* h     = ws + F_H;
    float* pc_t  = ws + F_PCT;
    float* pcn   = ws + F_PCN;
    unsigned short* wb   = (unsigned short*)(ws + WB_F);
    unsigned short* catl = wb + U_CATL;
    unsigned short* catr = wb + U_CATR;
    unsigned short* xb   = wb + U_XB;
    unsigned short* aob  = wb + U_AOB;
    unsigned short* hb   = wb + U_HB;
    unsigned short* ffb  = wb + U_FFB;

    detect_kernel<<<1, 256, 0, stream>>>(m_contact, dtf);

    wtrans_kernel<<<dim3(8, 36, 1), 256, 0, stream>>>(fc_lw, 0, CATD, HID, CATP, wb + W_FCL, 0, dtf);
    wtrans_kernel<<<dim3(8, 36, 1), 256, 0, stream>>>(fc_rw, 0, CATD, HID, CATP, wb + W_FCR, 0, dtf);
    wtrans_kernel<<<dim3(24, 8, NLAY), 256, 0, stream>>>(Wqkv, (size_t)HID*1536, HID, 1536, HID, wb + W_QKV, (size_t)1536*HID, dtf);
    wtrans_kernel<<<dim3(8, 8, NLAY), 256, 0, stream>>>(Wo, (size_t)HID*HID, HID, HID, HID, wb + W_WO, (size_t)HID*HID, dtf);
    wtrans_kernel<<<dim3(32, 8, NLAY), 256, 0, stream>>>(W1, (size_t)HID*2048, HID, 2048, HID, wb + W_W1, (size_t)2048*HID, dtf);
    wtrans_kernel<<<dim3(8, 32, NLAY), 256, 0, stream>>>(W2, (size_t)2048*HID, 2048, HID, 2048, wb + W_W2, (size_t)HID*2048, dtf);

    pct_kernel<<<B_ * L_, 256, 0, stream>>>(x_obj, point_cloud, pc_t, pcn, dtf);
    build_cat_kernel<<<dim3(B_ * L_, 2), 256, 0, stream>>>(
        x_lhand, j_lhand, x_rhand, j_rhand, m_contact, pc_t, pcn, catl, catr, dtf);

    // fc: M=1024,K=2304,N=512 -> 16x8 = 128 blocks; PE fused
    gemm_ks<<<128, 256, 0, stream>>>(catl, CATP, wb, W_FCL, HID, fc_lb, 0, nullptr, x, xb, 0, 1, 8, dtf);
    gemm_ks<<<128, 256, 0, stream>>>(catr, CATP, wb, W_FCR, HID, fc_rb, 0, nullptr, x, xb, 0, 2, 8, dtf);

    for (int i = 0; i < NLAY; i++) {
        size_t oWq = (size_t)W_QKV + (size_t)i * 1536 * HID, obq = (size_t)i * 1536;
        size_t oWo = (size_t)W_WO + (size_t)i * HID * HID,   obo = (size_t)i * HID;
        size_t oW1 = (size_t)W_W1 + (size_t)i * 2048 * HID,  ob1 = (size_t)i * 2048;
        size_t oW2 = (size_t)W_W2 + (size_t)i * HID * 2048,  ob2 = (size_t)i * HID;
        size_t oln = (size_t)i * HID;

        // qkv: 32x24 = 768 blocks
        gemm_ks<<<768, 256, 0, stream>>>(xb, HID, wb, oWq, 1536, bqkv, obq, nullptr, qkv, nullptr, 0, 0, 24, dtf);

        attn_scores_kernel<<<dim3(B_ * NHEAD, 4), 256, 0, stream>>>(qkv, probs);
        attn_av_kernel<<<dim3(B_ * NHEAD, 4), 256, 0, stream>>>(qkv, probs, aob);

        // Wo: 32x8 = 256 blocks
        gemm_ks<<<256, 256, 0, stream>>>(aob, HID, wb, oWo, HID, bo, obo, x, tmp, nullptr, 0, 0, 8, dtf);
        ln_kernel<<<T_, 256, 0, stream>>>(tmp, ln1g, ln1b, oln, h, hb, dtf);

        // W1: 32x32 = 1024 blocks (relu, bf16 out only)
        gemm_ks<<<1024, 256, 0, stream>>>(hb, HID, wb, oW1, 2048, b1f, ob1, nullptr, nullptr, ffb, 1, 0, 32, dtf);
        // W2: K=2048, 32x8 = 256 blocks
        gemm_ks<<<256, 256, 0, stream>>>(ffb, 2048, wb, oW2, HID, b2fp, ob2, h, tmp, nullptr, 0, 0, 8, dtf);
        ln_kernel<<<T_, 256, 0, stream>>>(tmp, ln2g, ln2b, oln, x, xb, dtf);
    }

    out_gemm_kernel<<<2 * B_ * L_, 128, 0, stream>>>(
        x, out_lw, out_lb, out_rw, out_rb, d_out, dtf);
}